// Round 2
// baseline (1322.327 us; speedup 1.0000x reference)
//
#include <hip/hip_runtime.h>
#include <hip/hip_bf16.h>

typedef __bf16 bf16_t;
typedef __bf16 bf16x8 __attribute__((ext_vector_type(8)));
typedef __bf16 bf16x4 __attribute__((ext_vector_type(4)));
typedef float  f32x4  __attribute__((ext_vector_type(4)));

#define B_    2
#define S_    2048
#define HID_  2048
#define H_    16
#define DH_   192
#define DR_   64
#define DN_   128
#define QL_   512
#define NROWS (B_*S_)          // 4096
#define QKD   (H_*DH_)         // 3072

#if __has_builtin(__builtin_amdgcn_exp2f)
#define EXP2(x) __builtin_amdgcn_exp2f(x)
#else
#define EXP2(x) exp2f(x)
#endif

// ---------------- cast f32 -> bf16 (vec4) ----------------
__global__ void cast_f32_to_bf16(const float* __restrict__ in, bf16_t* __restrict__ out, int n4) {
  int i = blockIdx.x * blockDim.x + threadIdx.x;
  if (i >= n4) return;
  const float4 v = reinterpret_cast<const float4*>(in)[i];
  bf16x4 r;
  r[0] = (bf16_t)v.x; r[1] = (bf16_t)v.y; r[2] = (bf16_t)v.z; r[3] = (bf16_t)v.w;
  reinterpret_cast<bf16x4*>(out)[i] = r;
}

// ---------------- generic bf16 MFMA GEMM ----------------
// C[M,N] = A[M,K] * B[K,N];  OMODE 0: f32 C, 1: bf16 C, 2: bf16 C^T (N x M)
#define BM 64
#define BN 64
#define BK 64
#define LDT 72

template<int OMODE>
__global__ __launch_bounds__(256) void gemm_kernel(
    const bf16_t* __restrict__ A, const bf16_t* __restrict__ B,
    void* __restrict__ C, int M, int N, int K) {
  __shared__ bf16_t sA[BM][LDT];
  __shared__ bf16_t sB[BN][LDT];   // transposed tile: [n][k]
  const int tid = threadIdx.x;
  const int w  = tid >> 6;
  const int l  = tid & 63;
  const int lg = l >> 4, lr = l & 15;
  const int m0 = blockIdx.y * BM, n0 = blockIdx.x * BN;

  f32x4 acc[4];
#pragma unroll
  for (int c = 0; c < 4; ++c) acc[c] = f32x4{0.f, 0.f, 0.f, 0.f};

  for (int k0 = 0; k0 < K; k0 += BK) {
#pragma unroll
    for (int i = 0; i < 2; ++i) {
      int cid = tid + i * 256;          // 0..511
      int row = cid >> 3;               // 0..63
      int cb  = (cid & 7) * 8;          // 0..56
      uint4 va = *reinterpret_cast<const uint4*>(&A[(size_t)(m0 + row) * K + k0 + cb]);
      *reinterpret_cast<uint4*>(&sA[row][cb]) = va;
      uint4 vb = *reinterpret_cast<const uint4*>(&B[(size_t)(k0 + row) * N + n0 + cb]);
      const bf16_t* pb = reinterpret_cast<const bf16_t*>(&vb);
#pragma unroll
      for (int e = 0; e < 8; ++e) sB[cb + e][row] = pb[e];
    }
    __syncthreads();
#pragma unroll
    for (int ks = 0; ks < 2; ++ks) {
      bf16x8 af = *reinterpret_cast<const bf16x8*>(&sA[w * 16 + lr][ks * 32 + lg * 8]);
#pragma unroll
      for (int c = 0; c < 4; ++c) {
        bf16x8 bfr = *reinterpret_cast<const bf16x8*>(&sB[c * 16 + lr][ks * 32 + lg * 8]);
        acc[c] = __builtin_amdgcn_mfma_f32_16x16x32_bf16(af, bfr, acc[c], 0, 0, 0);
      }
    }
    __syncthreads();
  }
#pragma unroll
  for (int c = 0; c < 4; ++c) {
#pragma unroll
    for (int r = 0; r < 4; ++r) {
      int row = m0 + w * 16 + lg * 4 + r;
      int col = n0 + c * 16 + lr;
      float v = acc[c][r];
      if (OMODE == 0)      ((float*)C)[(size_t)row * N + col]  = v;
      else if (OMODE == 1) ((bf16_t*)C)[(size_t)row * N + col] = (bf16_t)v;
      else                 ((bf16_t*)C)[(size_t)col * M + row] = (bf16_t)v;  // C^T
    }
  }
}

// ---------------- RMSNorm (in-place, one wave per row of 512) ----------------
__global__ __launch_bounds__(64) void rmsnorm_kernel(bf16_t* __restrict__ qa,
                                                     const float* __restrict__ wnorm) {
  int row = blockIdx.x;
  int l = threadIdx.x;
  bf16x8 v = *reinterpret_cast<const bf16x8*>(&qa[(size_t)row * QL_ + l * 8]);
  float f[8];
  float ss = 0.f;
#pragma unroll
  for (int e = 0; e < 8; ++e) { f[e] = (float)v[e]; ss += f[e] * f[e]; }
#pragma unroll
  for (int off = 32; off >= 1; off >>= 1) ss += __shfl_xor(ss, off);
  float rstd = rsqrtf(ss * (1.0f / 512.0f) + 1e-6f);
  bf16x8 o;
#pragma unroll
  for (int e = 0; e < 8; ++e) o[e] = (bf16_t)(f[e] * rstd * wnorm[l * 8 + e]);
  *reinterpret_cast<bf16x8*>(&qa[(size_t)row * QL_ + l * 8]) = o;
}

// ---------------- RoPE ----------------
__global__ void rope_q_kernel(bf16_t* __restrict__ q) {
  int idx = blockIdx.x * blockDim.x + threadIdx.x;  // NROWS*16*32
  int d   = idx & 31;
  int h   = (idx >> 5) & 15;
  int row = idx >> 9;
  if (row >= NROWS) return;
  int s = row & (S_ - 1);
  float freq = (float)s * expf(-(float)d * (9.210340371976184f / 32.0f));
  float sn, cs;
  sincosf(freq, &sn, &cs);
  size_t base = (size_t)row * QKD + h * DH_ + DN_ + d;
  float q1 = (float)q[base], q2 = (float)q[base + 32];
  q[base]      = (bf16_t)(q1 * cs - q2 * sn);
  q[base + 32] = (bf16_t)(q2 * cs + q1 * sn);
}

__global__ void rope_k_kernel(bf16_t* __restrict__ k) {
  int idx = blockIdx.x * blockDim.x + threadIdx.x;  // NROWS*32
  int d   = idx & 31;
  int row = idx >> 5;
  if (row >= NROWS) return;
  int s = row & (S_ - 1);
  float freq = (float)s * expf(-(float)d * (9.210340371976184f / 32.0f));
  float sn, cs;
  sincosf(freq, &sn, &cs);
  size_t base = (size_t)row * DH_ + DN_ + d;
  float k1 = (float)k[base], k2 = (float)k[base + 32];
  k[base]      = (bf16_t)(k1 * cs - k2 * sn);
  k[base + 32] = (bf16_t)(k2 * cs + k1 * sn);
}

// ---------------- causal flash attention with sink: barrier-free, direct-L2 ----------------
// Each wave independently handles 16 q-rows. K and V^T fragments read directly
// from global (K/V per batch = 1.57MB, L2-resident). LDS only for per-wave P tile.
#define SP_LDT 72

__global__ __launch_bounds__(256, 3) void attn_kernel(
    const bf16_t* __restrict__ q, const bf16_t* __restrict__ k,
    const bf16_t* __restrict__ vt, const float* __restrict__ sink,
    bf16_t* __restrict__ attn) {
  __shared__ bf16_t sP[4][16][SP_LDT];  // per-wave P: [qrow][key]
  const int tid = threadIdx.x;
  const int w  = tid >> 6;
  const int l  = tid & 63;
  const int lg = l >> 4, lr = l & 15;
  const int qx = blockIdx.x;
  const int qt = (qx & 1) ? (31 - (qx >> 1)) : (qx >> 1);  // long/short pairing
  const int bh = blockIdx.y;
  const int b  = bh >> 4, h = bh & 15;
  const int qrow0 = qt * 64 + w * 16;   // wave's first q row within sequence

  // Q fragments in registers for the whole kernel
  bf16x8 qf[6];
  {
    size_t rowoff = (size_t)(b * S_ + qrow0 + lr) * QKD + h * DH_;
#pragma unroll
    for (int ks = 0; ks < 6; ++ks)
      qf[ks] = *reinterpret_cast<const bf16x8*>(&q[rowoff + ks * 32 + lg * 8]);
  }

  f32x4 acc[12];
#pragma unroll
  for (int c = 0; c < 12; ++c) acc[c] = f32x4{0.f, 0.f, 0.f, 0.f};

  const float L2E = 1.4426950408889634f;
  float m[4], lden[4];
  float sk2 = sink[h] * L2E;
#pragma unroll
  for (int r = 0; r < 4; ++r) { m[r] = sk2; lden[r] = 1.0f; }

  const float scale2 = 0.10411754646447386f;  // 192^-0.5 * log2(e)

  const bf16_t* kb = k  + (size_t)(b * S_) * DH_;
  const bf16_t* vb = vt + (size_t)(b * S_);

  for (int kt = 0; kt <= qt; ++kt) {
    // ---- QK^T (K fragments straight from L2) ----
    f32x4 sc[4];
#pragma unroll
    for (int c = 0; c < 4; ++c) sc[c] = f32x4{0.f, 0.f, 0.f, 0.f};
#pragma unroll
    for (int c = 0; c < 4; ++c) {
      const bf16_t* kr = kb + (size_t)(kt * 64 + c * 16 + lr) * DH_ + lg * 8;
#pragma unroll
      for (int ks = 0; ks < 6; ++ks)
        sc[c] = __builtin_amdgcn_mfma_f32_16x16x32_bf16(
            qf[ks], *reinterpret_cast<const bf16x8*>(&kr[ks * 32]), sc[c], 0, 0, 0);
    }

    // ---- scale (log2 domain) + causal mask on diagonal tile ----
    float pv[4][4];
    const bool diag = (kt == qt);
#pragma unroll
    for (int c = 0; c < 4; ++c) {
#pragma unroll
      for (int r = 0; r < 4; ++r) {
        float s = sc[c][r] * scale2;
        if (diag && (c * 16 + lr) > (w * 16 + lg * 4 + r)) s = -1e30f;
        pv[c][r] = s;
      }
    }

    // ---- online softmax (exp2 domain) ----
    float rmax[4], alpha[4], psum[4];
#pragma unroll
    for (int r = 0; r < 4; ++r)
      rmax[r] = fmaxf(fmaxf(pv[0][r], pv[1][r]), fmaxf(pv[2][r], pv[3][r]));
#pragma unroll
    for (int off = 1; off < 16; off <<= 1) {
#pragma unroll
      for (int r = 0; r < 4; ++r) rmax[r] = fmaxf(rmax[r], __shfl_xor(rmax[r], off));
    }
#pragma unroll
    for (int r = 0; r < 4; ++r) {
      float mn = fmaxf(m[r], rmax[r]);
      alpha[r] = EXP2(m[r] - mn);
      m[r] = mn;
      psum[r] = 0.f;
    }
#pragma unroll
    for (int c = 0; c < 4; ++c) {
#pragma unroll
      for (int r = 0; r < 4; ++r) {
        float p = EXP2(pv[c][r] - m[r]);
        pv[c][r] = p;
        psum[r] += p;
      }
    }
#pragma unroll
    for (int off = 1; off < 16; off <<= 1) {
#pragma unroll
      for (int r = 0; r < 4; ++r) psum[r] += __shfl_xor(psum[r], off);
    }
#pragma unroll
    for (int r = 0; r < 4; ++r) lden[r] = lden[r] * alpha[r] + psum[r];
#pragma unroll
    for (int c = 0; c < 12; ++c) {
#pragma unroll
      for (int r = 0; r < 4; ++r) acc[c][r] *= alpha[r];
    }

    // ---- P -> per-wave LDS (no cross-wave sharing: no barrier needed) ----
#pragma unroll
    for (int c = 0; c < 4; ++c) {
#pragma unroll
      for (int r = 0; r < 4; ++r) sP[w][lg * 4 + r][c * 16 + lr] = (bf16_t)pv[c][r];
    }

    // ---- PV: acc += P(16x64) * V(64x192), V^T fragments straight from L2 ----
#pragma unroll
    for (int ks2 = 0; ks2 < 2; ++ks2) {
      bf16x8 pf = *reinterpret_cast<const bf16x8*>(&sP[w][lr][ks2 * 32 + lg * 8]);
      const bf16_t* vr = vb + (size_t)(lr) * NROWS + kt * 64 + ks2 * 32 + lg * 8;
#pragma unroll
      for (int c2 = 0; c2 < 12; ++c2) {
        bf16x8 vf = *reinterpret_cast<const bf16x8*>(&vr[(size_t)(c2 * 16) * NROWS]);
        acc[c2] = __builtin_amdgcn_mfma_f32_16x16x32_bf16(pf, vf, acc[c2], 0, 0, 0);
      }
    }
  }

  // ---- epilogue ----
  float rl[4];
#pragma unroll
  for (int r = 0; r < 4; ++r) rl[r] = 1.0f / lden[r];
#pragma unroll
  for (int c2 = 0; c2 < 12; ++c2) {
#pragma unroll
    for (int r = 0; r < 4; ++r) {
      int i = qrow0 + lg * 4 + r;
      size_t off = (size_t)(b * S_ + i) * QKD + h * DH_ + c2 * 16 + lr;
      attn[off] = (bf16_t)(acc[c2][r] * rl[r]);
    }
  }
}

// ---------------- launch ----------------
extern "C" void kernel_launch(void* const* d_in, const int* in_sizes, int n_in,
                              void* d_out, int out_size, void* d_ws, size_t ws_size,
                              hipStream_t stream) {
  const float* x        = (const float*)d_in[0];
  const float* w_qa     = (const float*)d_in[1];
  const float* q_norm_w = (const float*)d_in[2];
  const float* w_qb     = (const float*)d_in[3];
  const float* w_k      = (const float*)d_in[4];
  const float* w_v      = (const float*)d_in[5];
  const float* w_o      = (const float*)d_in[6];
  const float* attn_sink= (const float*)d_in[7];
  float* out = (float*)d_out;

  char* ws = (char*)d_ws;
  size_t off = 0;
  auto alloc = [&](size_t bytes) -> void* {
    void* p = ws + off;
    off += (bytes + 255) & ~(size_t)255;
    return p;
  };
  bf16_t* q_b  = (bf16_t*)alloc((size_t)NROWS * QKD * 2);
  bf16_t* k_b  = (bf16_t*)alloc((size_t)NROWS * DH_ * 2);
  bf16_t* vt_b = (bf16_t*)alloc((size_t)DH_ * NROWS * 2);
  bf16_t* wo_b = (bf16_t*)alloc((size_t)QKD * HID_ * 2);
  size_t temp_start = off;
  bf16_t* xb    = (bf16_t*)alloc((size_t)NROWS * HID_ * 2);
  bf16_t* wqa_b = (bf16_t*)alloc((size_t)HID_ * QL_ * 2);
  bf16_t* wqb_b = (bf16_t*)alloc((size_t)QL_ * QKD * 2);
  bf16_t* wk_b  = (bf16_t*)alloc((size_t)HID_ * DH_ * 2);
  bf16_t* wv_b  = (bf16_t*)alloc((size_t)HID_ * DH_ * 2);
  bf16_t* qa_b  = (bf16_t*)alloc((size_t)NROWS * QL_ * 2);
  bf16_t* attn_b = (bf16_t*)(ws + temp_start);   // overlays dead temps

  auto cast = [&](const float* src, bf16_t* dst, size_t n) {
    int n4 = (int)(n / 4);
    cast_f32_to_bf16<<<dim3((n4 + 255) / 256), dim3(256), 0, stream>>>(src, dst, n4);
  };
  cast(x,    xb,    (size_t)NROWS * HID_);
  cast(w_qa, wqa_b, (size_t)HID_ * QL_);
  cast(w_qb, wqb_b, (size_t)QL_ * QKD);
  cast(w_k,  wk_b,  (size_t)HID_ * DH_);
  cast(w_v,  wv_b,  (size_t)HID_ * DH_);
  cast(w_o,  wo_b,  (size_t)QKD * HID_);

  gemm_kernel<1><<<dim3(QL_ / BN, NROWS / BM), 256, 0, stream>>>(xb, wqa_b, qa_b, NROWS, QL_, HID_);
  rmsnorm_kernel<<<dim3(NROWS), dim3(64), 0, stream>>>(qa_b, q_norm_w);
  gemm_kernel<1><<<dim3(QKD / BN, NROWS / BM), 256, 0, stream>>>(qa_b, wqb_b, q_b, NROWS, QKD, QL_);
  gemm_kernel<1><<<dim3(DH_ / BN, NROWS / BM), 256, 0, stream>>>(xb, wk_b, k_b, NROWS, DH_, HID_);
  gemm_kernel<2><<<dim3(DH_ / BN, NROWS / BM), 256, 0, stream>>>(xb, wv_b, vt_b, NROWS, DH_, HID_);
  rope_q_kernel<<<dim3((NROWS * H_ * 32) / 256), dim3(256), 0, stream>>>(q_b);
  rope_k_kernel<<<dim3((NROWS * 32) / 256), dim3(256), 0, stream>>>(k_b);
  attn_kernel<<<dim3(S_ / 64, B_ * H_), dim3(256), 0, stream>>>(q_b, k_b, vt_b, attn_sink, attn_b);
  gemm_kernel<0><<<dim3(HID_ / BN, NROWS / BM), 256, 0, stream>>>(attn_b, wo_b, out, NROWS, HID_, QKD);
}

// Round 3
// 828.126 us; speedup vs baseline: 1.5968x; 1.5968x over previous
//
#include <hip/hip_runtime.h>
#include <hip/hip_bf16.h>

typedef __bf16 bf16_t;
typedef __bf16 bf16x8 __attribute__((ext_vector_type(8)));
typedef __bf16 bf16x4 __attribute__((ext_vector_type(4)));
typedef float  f32x4  __attribute__((ext_vector_type(4)));
typedef __attribute__((address_space(3))) unsigned int lds_u32_t;
typedef __attribute__((address_space(1))) const unsigned int glb_u32_t;

#define B_    2
#define S_    2048
#define HID_  2048
#define H_    16
#define DH_   192
#define DR_   64
#define DN_   128
#define QL_   512
#define NROWS (B_*S_)          // 4096
#define QKD   (H_*DH_)         // 3072

#if __has_builtin(__builtin_amdgcn_exp2f)
#define EXP2(x) __builtin_amdgcn_exp2f(x)
#else
#define EXP2(x) exp2f(x)
#endif

// ---------------- cast f32 -> bf16 (vec4) ----------------
__global__ void cast_f32_to_bf16(const float* __restrict__ in, bf16_t* __restrict__ out, int n4) {
  int i = blockIdx.x * blockDim.x + threadIdx.x;
  if (i >= n4) return;
  const float4 v = reinterpret_cast<const float4*>(in)[i];
  bf16x4 r;
  r[0] = (bf16_t)v.x; r[1] = (bf16_t)v.y; r[2] = (bf16_t)v.z; r[3] = (bf16_t)v.w;
  reinterpret_cast<bf16x4*>(out)[i] = r;
}

// ---------------- transpose-cast f32 [R][C] -> bf16 [C][R] ----------------
__global__ __launch_bounds__(256) void transpose_cast(
    const float* __restrict__ in, bf16_t* __restrict__ out, int R, int Cc) {
  __shared__ float t[32][33];
  const int tx = threadIdx.x & 31;
  const int ty = threadIdx.x >> 5;       // 0..7
  const int r0 = blockIdx.y * 32, c0 = blockIdx.x * 32;
#pragma unroll
  for (int j = 0; j < 4; ++j)
    t[ty + j * 8][tx] = in[(size_t)(r0 + ty + j * 8) * Cc + c0 + tx];
  __syncthreads();
#pragma unroll
  for (int j = 0; j < 4; ++j)
    out[(size_t)(c0 + ty + j * 8) * R + r0 + tx] = (bf16_t)t[tx][ty + j * 8];
}

// ---------------- generic bf16 MFMA GEMM, B^T input ----------------
// C[M,N] = A[M,K] * BT[N,K]^T;  OMODE 0: f32 C, 1: bf16 C, 2: bf16 C^T (N x M)
#define BM 64
#define BN 64
#define BK 64
#define LDT 72

template<int OMODE>
__global__ __launch_bounds__(256) void gemm_kernel(
    const bf16_t* __restrict__ A, const bf16_t* __restrict__ BT,
    void* __restrict__ C, int M, int N, int K) {
  __shared__ __align__(16) bf16_t sA[BM][LDT];
  __shared__ __align__(16) bf16_t sB[BN][LDT];
  const int tid = threadIdx.x;
  const int w  = tid >> 6;
  const int l  = tid & 63;
  const int lg = l >> 4, lr = l & 15;
  const int m0 = blockIdx.y * BM, n0 = blockIdx.x * BN;

  f32x4 acc[4];
#pragma unroll
  for (int c = 0; c < 4; ++c) acc[c] = f32x4{0.f, 0.f, 0.f, 0.f};

  for (int k0 = 0; k0 < K; k0 += BK) {
#pragma unroll
    for (int i = 0; i < 2; ++i) {
      int cid = tid + i * 256;          // 0..511
      int row = cid >> 3;               // 0..63
      int cb  = (cid & 7) * 8;          // 0..56
      *reinterpret_cast<uint4*>(&sA[row][cb]) =
          *reinterpret_cast<const uint4*>(&A[(size_t)(m0 + row) * K + k0 + cb]);
      *reinterpret_cast<uint4*>(&sB[row][cb]) =
          *reinterpret_cast<const uint4*>(&BT[(size_t)(n0 + row) * K + k0 + cb]);
    }
    __syncthreads();
#pragma unroll
    for (int ks = 0; ks < 2; ++ks) {
      bf16x8 af = *reinterpret_cast<const bf16x8*>(&sA[w * 16 + lr][ks * 32 + lg * 8]);
#pragma unroll
      for (int c = 0; c < 4; ++c) {
        bf16x8 bfr = *reinterpret_cast<const bf16x8*>(&sB[c * 16 + lr][ks * 32 + lg * 8]);
        acc[c] = __builtin_amdgcn_mfma_f32_16x16x32_bf16(af, bfr, acc[c], 0, 0, 0);
      }
    }
    __syncthreads();
  }
#pragma unroll
  for (int c = 0; c < 4; ++c) {
#pragma unroll
    for (int r = 0; r < 4; ++r) {
      int row = m0 + w * 16 + lg * 4 + r;
      int col = n0 + c * 16 + lr;
      float v = acc[c][r];
      if (OMODE == 0)      ((float*)C)[(size_t)row * N + col]  = v;
      else if (OMODE == 1) ((bf16_t*)C)[(size_t)row * N + col] = (bf16_t)v;
      else                 ((bf16_t*)C)[(size_t)col * M + row] = (bf16_t)v;  // C^T
    }
  }
}

// ---------------- RMSNorm (in-place, one wave per row of 512) ----------------
__global__ __launch_bounds__(64) void rmsnorm_kernel(bf16_t* __restrict__ qa,
                                                     const float* __restrict__ wnorm) {
  int row = blockIdx.x;
  int l = threadIdx.x;
  bf16x8 v = *reinterpret_cast<const bf16x8*>(&qa[(size_t)row * QL_ + l * 8]);
  float f[8];
  float ss = 0.f;
#pragma unroll
  for (int e = 0; e < 8; ++e) { f[e] = (float)v[e]; ss += f[e] * f[e]; }
#pragma unroll
  for (int off = 32; off >= 1; off >>= 1) ss += __shfl_xor(ss, off);
  float rstd = rsqrtf(ss * (1.0f / 512.0f) + 1e-6f);
  bf16x8 o;
#pragma unroll
  for (int e = 0; e < 8; ++e) o[e] = (bf16_t)(f[e] * rstd * wnorm[l * 8 + e]);
  *reinterpret_cast<bf16x8*>(&qa[(size_t)row * QL_ + l * 8]) = o;
}

// ---------------- RoPE ----------------
__global__ void rope_q_kernel(bf16_t* __restrict__ q) {
  int idx = blockIdx.x * blockDim.x + threadIdx.x;  // NROWS*16*32
  int d   = idx & 31;
  int h   = (idx >> 5) & 15;
  int row = idx >> 9;
  if (row >= NROWS) return;
  int s = row & (S_ - 1);
  float freq = (float)s * expf(-(float)d * (9.210340371976184f / 32.0f));
  float sn, cs;
  sincosf(freq, &sn, &cs);
  size_t base = (size_t)row * QKD + h * DH_ + DN_ + d;
  float q1 = (float)q[base], q2 = (float)q[base + 32];
  q[base]      = (bf16_t)(q1 * cs - q2 * sn);
  q[base + 32] = (bf16_t)(q2 * cs + q1 * sn);
}

__global__ void rope_k_kernel(bf16_t* __restrict__ k) {
  int idx = blockIdx.x * blockDim.x + threadIdx.x;  // NROWS*32
  int d   = idx & 31;
  int row = idx >> 5;
  if (row >= NROWS) return;
  int s = row & (S_ - 1);
  float freq = (float)s * expf(-(float)d * (9.210340371976184f / 32.0f));
  float sn, cs;
  sincosf(freq, &sn, &cs);
  size_t base = (size_t)row * DH_ + DN_ + d;
  float k1 = (float)k[base], k2 = (float)k[base + 32];
  k[base]      = (bf16_t)(k1 * cs - k2 * sn);
  k[base + 32] = (bf16_t)(k2 * cs + k1 * sn);
}

// ---------------- causal flash attention with sink ----------------
// K tile staged via global_load_lds (linear dest, XOR-swizzled source/read);
// V^T direct from L2; per-wave P tile in LDS; 2 barriers/tile, staging of
// tile kt+1 overlaps softmax+PV of tile kt.
#define SP_LDT 72

__global__ __launch_bounds__(256, 4) void attn_kernel(
    const bf16_t* __restrict__ q, const bf16_t* __restrict__ k,
    const bf16_t* __restrict__ vt, const float* __restrict__ sink,
    bf16_t* __restrict__ attn) {
  __shared__ __align__(16) bf16_t sK[64 * 192];     // 24 KB, swizzled content
  __shared__ __align__(16) bf16_t sP[4][16][SP_LDT];
  const int tid = threadIdx.x;
  const int w  = tid >> 6;
  const int l  = tid & 63;
  const int lg = l >> 4, lr = l & 15;
  const int qx = blockIdx.x;
  const int qt = (qx & 1) ? (31 - (qx >> 1)) : (qx >> 1);  // long/short pairing
  const int bh = blockIdx.y;
  const int b  = bh >> 4, h = bh & 15;
  const int qrow0 = qt * 64 + w * 16;

  const bf16_t* kb = k  + (size_t)(b * S_) * DH_;
  const bf16_t* vb = vt + (size_t)(b * S_);

  // async-stage K tile kt: LDS linear, global source chunk-XOR-swizzled.
  // element K[row][ch*8..] lands at LDS chunk (ch ^ (row&7)).
  auto stageK = [&](int kt) {
    const bf16_t* kt_base = kb + (size_t)kt * 64 * DH_;
#pragma unroll
    for (int i = 0; i < 6; ++i) {
      int g = (w * 6 + i) * 64 + l;          // 0..1535 chunk id (linear LDS)
      int row = g / 24, ch = g % 24;
      int sch = ch ^ (row & 7);
      const bf16_t* gp = kt_base + row * DH_ + sch * 8;
      __builtin_amdgcn_global_load_lds((glb_u32_t*)gp,
                                       (lds_u32_t*)(sK + (w * 6 + i) * 512),
                                       16, 0, 0);
    }
  };

  // Q fragments in registers for the whole kernel
  bf16x8 qf[6];
  {
    size_t rowoff = (size_t)(b * S_ + qrow0 + lr) * QKD + h * DH_;
#pragma unroll
    for (int ks = 0; ks < 6; ++ks)
      qf[ks] = *reinterpret_cast<const bf16x8*>(&q[rowoff + ks * 32 + lg * 8]);
  }

  f32x4 acc[12];
#pragma unroll
  for (int c = 0; c < 12; ++c) acc[c] = f32x4{0.f, 0.f, 0.f, 0.f};

  const float L2E = 1.4426950408889634f;
  float m[4], lden[4];
  float sk2 = sink[h] * L2E;
#pragma unroll
  for (int r = 0; r < 4; ++r) { m[r] = sk2; lden[r] = 1.0f; }

  const float scale2 = 0.10411754646447386f;  // 192^-0.5 * log2(e)

  stageK(0);

  for (int kt = 0; kt <= qt; ++kt) {
    asm volatile("s_waitcnt vmcnt(0)" ::: "memory");
    __syncthreads();                       // sK[kt] visible to all waves

    // ---- QK^T from swizzled sK ----
    f32x4 sc[4];
#pragma unroll
    for (int c = 0; c < 4; ++c) sc[c] = f32x4{0.f, 0.f, 0.f, 0.f};
#pragma unroll
    for (int c = 0; c < 4; ++c) {
      const int row = c * 16 + lr;
      const int rx  = row & 7;
      const bf16_t* kr = sK + row * 192;
#pragma unroll
      for (int ks = 0; ks < 6; ++ks) {
        bf16x8 kf = *reinterpret_cast<const bf16x8*>(kr + (((ks * 4 + lg) ^ rx) << 3));
        sc[c] = __builtin_amdgcn_mfma_f32_16x16x32_bf16(qf[ks], kf, sc[c], 0, 0, 0);
      }
    }
    __syncthreads();                       // all waves done reading sK[kt]
    if (kt < qt) stageK(kt + 1);           // async prefetch under softmax+PV

    // ---- scale (log2 domain) + causal mask on diagonal tile ----
    float pv[4][4];
    const bool diag = (kt == qt);
#pragma unroll
    for (int c = 0; c < 4; ++c) {
#pragma unroll
      for (int r = 0; r < 4; ++r) {
        float s = sc[c][r] * scale2;
        if (diag && (c * 16 + lr) > (w * 16 + lg * 4 + r)) s = -1e30f;
        pv[c][r] = s;
      }
    }

    // ---- online softmax (exp2 domain) ----
    float rmax[4], alpha[4], psum[4];
#pragma unroll
    for (int r = 0; r < 4; ++r)
      rmax[r] = fmaxf(fmaxf(pv[0][r], pv[1][r]), fmaxf(pv[2][r], pv[3][r]));
#pragma unroll
    for (int off = 1; off < 16; off <<= 1) {
#pragma unroll
      for (int r = 0; r < 4; ++r) rmax[r] = fmaxf(rmax[r], __shfl_xor(rmax[r], off));
    }
#pragma unroll
    for (int r = 0; r < 4; ++r) {
      float mn = fmaxf(m[r], rmax[r]);
      alpha[r] = EXP2(m[r] - mn);
      m[r] = mn;
      psum[r] = 0.f;
    }
#pragma unroll
    for (int c = 0; c < 4; ++c) {
#pragma unroll
      for (int r = 0; r < 4; ++r) {
        float p = EXP2(pv[c][r] - m[r]);
        pv[c][r] = p;
        psum[r] += p;
      }
    }
#pragma unroll
    for (int off = 1; off < 16; off <<= 1) {
#pragma unroll
      for (int r = 0; r < 4; ++r) psum[r] += __shfl_xor(psum[r], off);
    }
#pragma unroll
    for (int r = 0; r < 4; ++r) lden[r] = lden[r] * alpha[r] + psum[r];
#pragma unroll
    for (int c = 0; c < 12; ++c) {
#pragma unroll
      for (int r = 0; r < 4; ++r) acc[c][r] *= alpha[r];
    }

    // ---- P -> per-wave LDS (same-wave reuse only) ----
#pragma unroll
    for (int c = 0; c < 4; ++c) {
#pragma unroll
      for (int r = 0; r < 4; ++r) sP[w][lg * 4 + r][c * 16 + lr] = (bf16_t)pv[c][r];
    }

    // ---- PV: acc += P(16x64) * V(64x192), V^T fragments from L2 ----
#pragma unroll
    for (int ks2 = 0; ks2 < 2; ++ks2) {
      bf16x8 pf = *reinterpret_cast<const bf16x8*>(&sP[w][lr][ks2 * 32 + lg * 8]);
      const bf16_t* vr = vb + (size_t)(lr) * NROWS + kt * 64 + ks2 * 32 + lg * 8;
#pragma unroll
      for (int c2 = 0; c2 < 12; ++c2) {
        bf16x8 vf = *reinterpret_cast<const bf16x8*>(&vr[(size_t)(c2 * 16) * NROWS]);
        acc[c2] = __builtin_amdgcn_mfma_f32_16x16x32_bf16(pf, vf, acc[c2], 0, 0, 0);
      }
    }
  }

  // ---- epilogue ----
  float rl[4];
#pragma unroll
  for (int r = 0; r < 4; ++r) rl[r] = 1.0f / lden[r];
#pragma unroll
  for (int c2 = 0; c2 < 12; ++c2) {
#pragma unroll
    for (int r = 0; r < 4; ++r) {
      int i = qrow0 + lg * 4 + r;
      size_t off = (size_t)(b * S_ + i) * QKD + h * DH_ + c2 * 16 + lr;
      attn[off] = (bf16_t)(acc[c2][r] * rl[r]);
    }
  }
}

// ---------------- launch ----------------
extern "C" void kernel_launch(void* const* d_in, const int* in_sizes, int n_in,
                              void* d_out, int out_size, void* d_ws, size_t ws_size,
                              hipStream_t stream) {
  const float* x        = (const float*)d_in[0];
  const float* w_qa     = (const float*)d_in[1];
  const float* q_norm_w = (const float*)d_in[2];
  const float* w_qb     = (const float*)d_in[3];
  const float* w_k      = (const float*)d_in[4];
  const float* w_v      = (const float*)d_in[5];
  const float* w_o      = (const float*)d_in[6];
  const float* attn_sink= (const float*)d_in[7];
  float* out = (float*)d_out;

  char* ws = (char*)d_ws;
  size_t off = 0;
  auto alloc = [&](size_t bytes) -> void* {
    void* p = ws + off;
    off += (bytes + 255) & ~(size_t)255;
    return p;
  };
  bf16_t* q_b  = (bf16_t*)alloc((size_t)NROWS * QKD * 2);
  bf16_t* k_b  = (bf16_t*)alloc((size_t)NROWS * DH_ * 2);
  bf16_t* vt_b = (bf16_t*)alloc((size_t)DH_ * NROWS * 2);
  bf16_t* wo_t = (bf16_t*)alloc((size_t)HID_ * QKD * 2);   // w_o^T [2048][3072]
  size_t temp_start = off;
  bf16_t* xb    = (bf16_t*)alloc((size_t)NROWS * HID_ * 2);
  bf16_t* wqa_t = (bf16_t*)alloc((size_t)QL_ * HID_ * 2);  // [512][2048]
  bf16_t* wqb_t = (bf16_t*)alloc((size_t)QKD * QL_ * 2);   // [3072][512]
  bf16_t* wk_t  = (bf16_t*)alloc((size_t)DH_ * HID_ * 2);  // [192][2048]
  bf16_t* wv_t  = (bf16_t*)alloc((size_t)DH_ * HID_ * 2);  // [192][2048]
  bf16_t* qa_b  = (bf16_t*)alloc((size_t)NROWS * QL_ * 2);
  bf16_t* attn_b = (bf16_t*)(ws + temp_start);             // overlays dead temps

  int n4x = (int)((size_t)NROWS * HID_ / 4);
  cast_f32_to_bf16<<<dim3((n4x + 255) / 256), dim3(256), 0, stream>>>(x, xb, n4x);
  // weights: transpose-cast f32 [R][C] -> bf16 [C][R]
  transpose_cast<<<dim3(QL_ / 32, HID_ / 32), 256, 0, stream>>>(w_qa, wqa_t, HID_, QL_);
  transpose_cast<<<dim3(QKD / 32, QL_ / 32), 256, 0, stream>>>(w_qb, wqb_t, QL_, QKD);
  transpose_cast<<<dim3(DH_ / 32, HID_ / 32), 256, 0, stream>>>(w_k, wk_t, HID_, DH_);
  transpose_cast<<<dim3(DH_ / 32, HID_ / 32), 256, 0, stream>>>(w_v, wv_t, HID_, DH_);
  transpose_cast<<<dim3(HID_ / 32, QKD / 32), 256, 0, stream>>>(w_o, wo_t, QKD, HID_);

  gemm_kernel<1><<<dim3(QL_ / BN, NROWS / BM), 256, 0, stream>>>(xb, wqa_t, qa_b, NROWS, QL_, HID_);
  rmsnorm_kernel<<<dim3(NROWS), dim3(64), 0, stream>>>(qa_b, q_norm_w);
  gemm_kernel<1><<<dim3(QKD / BN, NROWS / BM), 256, 0, stream>>>(qa_b, wqb_t, q_b, NROWS, QKD, QL_);
  gemm_kernel<1><<<dim3(DH_ / BN, NROWS / BM), 256, 0, stream>>>(xb, wk_t, k_b, NROWS, DH_, HID_);
  gemm_kernel<2><<<dim3(DH_ / BN, NROWS / BM), 256, 0, stream>>>(xb, wv_t, vt_b, NROWS, DH_, HID_);
  rope_q_kernel<<<dim3((NROWS * H_ * 32) / 256), dim3(256), 0, stream>>>(q_b);
  rope_k_kernel<<<dim3((NROWS * 32) / 256), dim3(256), 0, stream>>>(k_b);
  attn_kernel<<<dim3(S_ / 64, B_ * H_), dim3(256), 0, stream>>>(q_b, k_b, vt_b, attn_sink, attn_b);
  gemm_kernel<0><<<dim3(HID_ / BN, NROWS / BM), 256, 0, stream>>>(attn_b, wo_t, out, NROWS, HID_, QKD);
}

// Round 4
// 491.062 us; speedup vs baseline: 2.6928x; 1.6864x over previous
//
#include <hip/hip_runtime.h>
#include <hip/hip_bf16.h>

typedef __bf16 bf16_t;
typedef __bf16 bf16x8 __attribute__((ext_vector_type(8)));
typedef __bf16 bf16x4 __attribute__((ext_vector_type(4)));
typedef float  f32x4  __attribute__((ext_vector_type(4)));
typedef __attribute__((address_space(3))) unsigned int lds_u32_t;
typedef __attribute__((address_space(1))) const unsigned int glb_u32_t;

#define B_    2
#define S_    2048
#define HID_  2048
#define H_    16
#define DH_   192
#define DR_   64
#define DN_   128
#define QL_   512
#define NROWS (B_*S_)          // 4096
#define QKD   (H_*DH_)         // 3072

#if __has_builtin(__builtin_amdgcn_exp2f)
#define EXP2(x) __builtin_amdgcn_exp2f(x)
#else
#define EXP2(x) exp2f(x)
#endif

// ---------------- cast f32 -> bf16 (vec4) ----------------
__global__ void cast_f32_to_bf16(const float* __restrict__ in, bf16_t* __restrict__ out, int n4) {
  int i = blockIdx.x * blockDim.x + threadIdx.x;
  if (i >= n4) return;
  const float4 v = reinterpret_cast<const float4*>(in)[i];
  bf16x4 r;
  r[0] = (bf16_t)v.x; r[1] = (bf16_t)v.y; r[2] = (bf16_t)v.z; r[3] = (bf16_t)v.w;
  reinterpret_cast<bf16x4*>(out)[i] = r;
}

// ---------------- transpose-cast f32 [R][C] -> bf16 [C][R] ----------------
__global__ __launch_bounds__(256) void transpose_cast(
    const float* __restrict__ in, bf16_t* __restrict__ out, int R, int Cc) {
  __shared__ float t[32][33];
  const int tx = threadIdx.x & 31;
  const int ty = threadIdx.x >> 5;       // 0..7
  const int r0 = blockIdx.y * 32, c0 = blockIdx.x * 32;
#pragma unroll
  for (int j = 0; j < 4; ++j)
    t[ty + j * 8][tx] = in[(size_t)(r0 + ty + j * 8) * Cc + c0 + tx];
  __syncthreads();
#pragma unroll
  for (int j = 0; j < 4; ++j)
    out[(size_t)(c0 + ty + j * 8) * R + r0 + tx] = (bf16_t)t[tx][ty + j * 8];
}

// ---------------- generic bf16 MFMA GEMM, B^T input ----------------
// C[M,N] = A[M,K] * BT[N,K]^T;  OMODE 0: f32 C, 1: bf16 C, 2: bf16 C^T (N x M)
#define BM 64
#define BN 64
#define BK 64
#define LDT 72

template<int OMODE>
__global__ __launch_bounds__(256) void gemm_kernel(
    const bf16_t* __restrict__ A, const bf16_t* __restrict__ BT,
    void* __restrict__ C, int M, int N, int K) {
  __shared__ __align__(16) bf16_t sA[BM][LDT];
  __shared__ __align__(16) bf16_t sB[BN][LDT];
  const int tid = threadIdx.x;
  const int w  = tid >> 6;
  const int l  = tid & 63;
  const int lg = l >> 4, lr = l & 15;
  const int m0 = blockIdx.y * BM, n0 = blockIdx.x * BN;

  f32x4 acc[4];
#pragma unroll
  for (int c = 0; c < 4; ++c) acc[c] = f32x4{0.f, 0.f, 0.f, 0.f};

  for (int k0 = 0; k0 < K; k0 += BK) {
#pragma unroll
    for (int i = 0; i < 2; ++i) {
      int cid = tid + i * 256;          // 0..511
      int row = cid >> 3;               // 0..63
      int cb  = (cid & 7) * 8;          // 0..56
      *reinterpret_cast<uint4*>(&sA[row][cb]) =
          *reinterpret_cast<const uint4*>(&A[(size_t)(m0 + row) * K + k0 + cb]);
      *reinterpret_cast<uint4*>(&sB[row][cb]) =
          *reinterpret_cast<const uint4*>(&BT[(size_t)(n0 + row) * K + k0 + cb]);
    }
    __syncthreads();
#pragma unroll
    for (int ks = 0; ks < 2; ++ks) {
      bf16x8 af = *reinterpret_cast<const bf16x8*>(&sA[w * 16 + lr][ks * 32 + lg * 8]);
#pragma unroll
      for (int c = 0; c < 4; ++c) {
        bf16x8 bfr = *reinterpret_cast<const bf16x8*>(&sB[c * 16 + lr][ks * 32 + lg * 8]);
        acc[c] = __builtin_amdgcn_mfma_f32_16x16x32_bf16(af, bfr, acc[c], 0, 0, 0);
      }
    }
    __syncthreads();
  }
#pragma unroll
  for (int c = 0; c < 4; ++c) {
#pragma unroll
    for (int r = 0; r < 4; ++r) {
      int row = m0 + w * 16 + lg * 4 + r;
      int col = n0 + c * 16 + lr;
      float v = acc[c][r];
      if (OMODE == 0)      ((float*)C)[(size_t)row * N + col]  = v;
      else if (OMODE == 1) ((bf16_t*)C)[(size_t)row * N + col] = (bf16_t)v;
      else                 ((bf16_t*)C)[(size_t)col * M + row] = (bf16_t)v;  // C^T
    }
  }
}

// ---------------- RMSNorm (in-place, one wave per row of 512) ----------------
__global__ __launch_bounds__(64) void rmsnorm_kernel(bf16_t* __restrict__ qa,
                                                     const float* __restrict__ wnorm) {
  int row = blockIdx.x;
  int l = threadIdx.x;
  bf16x8 v = *reinterpret_cast<const bf16x8*>(&qa[(size_t)row * QL_ + l * 8]);
  float f[8];
  float ss = 0.f;
#pragma unroll
  for (int e = 0; e < 8; ++e) { f[e] = (float)v[e]; ss += f[e] * f[e]; }
#pragma unroll
  for (int off = 32; off >= 1; off >>= 1) ss += __shfl_xor(ss, off);
  float rstd = rsqrtf(ss * (1.0f / 512.0f) + 1e-6f);
  bf16x8 o;
#pragma unroll
  for (int e = 0; e < 8; ++e) o[e] = (bf16_t)(f[e] * rstd * wnorm[l * 8 + e]);
  *reinterpret_cast<bf16x8*>(&qa[(size_t)row * QL_ + l * 8]) = o;
}

// ---------------- RoPE ----------------
__global__ void rope_q_kernel(bf16_t* __restrict__ q) {
  int idx = blockIdx.x * blockDim.x + threadIdx.x;  // NROWS*16*32
  int d   = idx & 31;
  int h   = (idx >> 5) & 15;
  int row = idx >> 9;
  if (row >= NROWS) return;
  int s = row & (S_ - 1);
  float freq = (float)s * expf(-(float)d * (9.210340371976184f / 32.0f));
  float sn, cs;
  sincosf(freq, &sn, &cs);
  size_t base = (size_t)row * QKD + h * DH_ + DN_ + d;
  float q1 = (float)q[base], q2 = (float)q[base + 32];
  q[base]      = (bf16_t)(q1 * cs - q2 * sn);
  q[base + 32] = (bf16_t)(q2 * cs + q1 * sn);
}

__global__ void rope_k_kernel(bf16_t* __restrict__ k) {
  int idx = blockIdx.x * blockDim.x + threadIdx.x;  // NROWS*32
  int d   = idx & 31;
  int row = idx >> 5;
  if (row >= NROWS) return;
  int s = row & (S_ - 1);
  float freq = (float)s * expf(-(float)d * (9.210340371976184f / 32.0f));
  float sn, cs;
  sincosf(freq, &sn, &cs);
  size_t base = (size_t)row * DH_ + DN_ + d;
  float k1 = (float)k[base], k2 = (float)k[base + 32];
  k[base]      = (bf16_t)(k1 * cs - k2 * sn);
  k[base + 32] = (bf16_t)(k2 * cs + k1 * sn);
}

// ---------------- causal flash attention with sink ----------------
// Block = 128 q-rows x one (b,h). 4 waves, each wave 32 q-rows (2 row-frags).
// K and V tiles (KB=32) double-buffered in LDS via global_load_lds with
// XOR-swizzled source+read (linear LDS dest). One barrier per tile; prefetch
// of tile kt+1 stays in flight across softmax+PV of tile kt.
#define KB32  32
#define SPLD  40   // sP row stride (bf16 elems), 16B-multiple

__global__ __launch_bounds__(256, 2) void attn_kernel(
    const bf16_t* __restrict__ q, const bf16_t* __restrict__ k,
    const bf16_t* __restrict__ vt, const float* __restrict__ sink,
    bf16_t* __restrict__ attn) {
  __shared__ __align__(16) bf16_t sK[2][KB32 * DH_];   // 2 x 12KB, swizzled
  __shared__ __align__(16) bf16_t sV[2][DH_ * KB32];   // 2 x 12KB, swizzled V^T
  __shared__ __align__(16) bf16_t sP[4][32][SPLD];     // 10KB
  const int tid = threadIdx.x;
  const int w  = tid >> 6;
  const int l  = tid & 63;
  const int lg = l >> 4, lr = l & 15;
  const int x  = blockIdx.x;
  const int qt = x >> 5;            // 0..15 (128-row q tile)
  const int bh = x & 31;
  const int b  = bh >> 4, h = bh & 15;
  const int wrow0 = qt * 128 + w * 32;     // wave's first q row
  const int ktmax_w = 4 * qt + w;          // last tile this wave computes
  const int ktmax_b = 4 * qt + 3;          // last tile staged by block

  const bf16_t* kb = k + (size_t)(b * S_) * DH_;

  // precomputed staging offsets (per thread, per i)
  int koff[3], voff[3], ldst[3];
#pragma unroll
  for (int i = 0; i < 3; ++i) {
    int g = i * 256 + tid;                 // 0..767 chunk id
    int krow = g / 24, kch = g - krow * 24;
    koff[i] = krow * DH_ + ((kch ^ (krow & 7)) << 3);
    int vrow = g >> 2, vch = g & 3;
    voff[i] = vrow * NROWS + ((vch ^ (vrow & 3)) << 3);
    ldst[i] = (i * 256 + w * 64) * 8;      // linear LDS elem offset (wave-uniform)
  }

  auto stage = [&](int kt, int bu) {
    const bf16_t* ksrc = kb + (size_t)kt * KB32 * DH_;
    const bf16_t* vsrc = vt + (size_t)(b * S_ + kt * KB32);
#pragma unroll
    for (int i = 0; i < 3; ++i) {
      __builtin_amdgcn_global_load_lds((glb_u32_t*)(ksrc + koff[i]),
                                       (lds_u32_t*)(&sK[bu][0] + ldst[i]), 16, 0, 0);
      __builtin_amdgcn_global_load_lds((glb_u32_t*)(vsrc + voff[i]),
                                       (lds_u32_t*)(&sV[bu][0] + ldst[i]), 16, 0, 0);
    }
  };

  // Q fragments in registers for the whole kernel: 2 row-frags x 6 k-slices
  bf16x8 qf[2][6];
#pragma unroll
  for (int rf = 0; rf < 2; ++rf) {
    size_t rowoff = (size_t)(b * S_ + wrow0 + rf * 16 + lr) * QKD + h * DH_;
#pragma unroll
    for (int ks = 0; ks < 6; ++ks)
      qf[rf][ks] = *reinterpret_cast<const bf16x8*>(&q[rowoff + ks * 32 + lg * 8]);
  }

  f32x4 acc[2][12];
#pragma unroll
  for (int rf = 0; rf < 2; ++rf)
#pragma unroll
    for (int c = 0; c < 12; ++c) acc[rf][c] = f32x4{0.f, 0.f, 0.f, 0.f};

  const float L2E = 1.4426950408889634f;
  float m[2][4], lden[2][4];
  float sk2 = sink[h] * L2E;
#pragma unroll
  for (int rf = 0; rf < 2; ++rf)
#pragma unroll
    for (int r = 0; r < 4; ++r) { m[rf][r] = sk2; lden[rf][r] = 1.0f; }

  const float scale2 = 0.10411754646447386f;  // 192^-0.5 * log2(e)

  stage(0, 0);
  int cur = 0;

  for (int kt = 0; kt <= ktmax_b; ++kt) {
    asm volatile("s_waitcnt vmcnt(0)" ::: "memory");
    __syncthreads();                      // buffers[cur] ready for all waves

    if (kt < ktmax_b) stage(kt + 1, cur ^ 1);   // prefetch next tile

    const bool active = (kt <= ktmax_w);
    if (active) {
      // ---- QK^T: sc[rf][c], col = key c*16+lr, row = qrow rf*16+lg*4+r ----
      f32x4 sc[2][2];
#pragma unroll
      for (int rf = 0; rf < 2; ++rf)
#pragma unroll
        for (int c = 0; c < 2; ++c) sc[rf][c] = f32x4{0.f, 0.f, 0.f, 0.f};
#pragma unroll
      for (int c = 0; c < 2; ++c) {
        const int row = c * 16 + lr;
        const int rx  = row & 7;
        const bf16_t* kr = &sK[cur][0] + row * DH_;
#pragma unroll
        for (int ks = 0; ks < 6; ++ks) {
          bf16x8 kf = *reinterpret_cast<const bf16x8*>(kr + (((ks * 4 + lg) ^ rx) << 3));
          sc[0][c] = __builtin_amdgcn_mfma_f32_16x16x32_bf16(qf[0][ks], kf, sc[0][c], 0, 0, 0);
          sc[1][c] = __builtin_amdgcn_mfma_f32_16x16x32_bf16(qf[1][ks], kf, sc[1][c], 0, 0, 0);
        }
      }

      // ---- scale + causal mask (only wave-diagonal tile is partial) ----
      float pv[2][2][4];
      const bool diag = (kt == ktmax_w);
#pragma unroll
      for (int rf = 0; rf < 2; ++rf)
#pragma unroll
        for (int c = 0; c < 2; ++c)
#pragma unroll
          for (int r = 0; r < 4; ++r) {
            float s = sc[rf][c][r] * scale2;
            if (diag && (c * 16 + lr) > (rf * 16 + lg * 4 + r)) s = -1e30f;
            pv[rf][c][r] = s;
          }

      // ---- online softmax (exp2 domain), rows across 16 lanes ----
#pragma unroll
      for (int rf = 0; rf < 2; ++rf) {
        float rmax[4], alpha[4], psum[4];
#pragma unroll
        for (int r = 0; r < 4; ++r) rmax[r] = fmaxf(pv[rf][0][r], pv[rf][1][r]);
#pragma unroll
        for (int off = 1; off < 16; off <<= 1) {
#pragma unroll
          for (int r = 0; r < 4; ++r) rmax[r] = fmaxf(rmax[r], __shfl_xor(rmax[r], off));
        }
#pragma unroll
        for (int r = 0; r < 4; ++r) {
          float mn = fmaxf(m[rf][r], rmax[r]);
          alpha[r] = EXP2(m[rf][r] - mn);
          m[rf][r] = mn;
          psum[r] = 0.f;
        }
#pragma unroll
        for (int c = 0; c < 2; ++c)
#pragma unroll
          for (int r = 0; r < 4; ++r) {
            float p = EXP2(pv[rf][c][r] - m[rf][r]);
            pv[rf][c][r] = p;
            psum[r] += p;
          }
#pragma unroll
        for (int off = 1; off < 16; off <<= 1) {
#pragma unroll
          for (int r = 0; r < 4; ++r) psum[r] += __shfl_xor(psum[r], off);
        }
#pragma unroll
        for (int r = 0; r < 4; ++r) lden[rf][r] = lden[rf][r] * alpha[r] + psum[r];
#pragma unroll
        for (int c = 0; c < 12; ++c)
#pragma unroll
          for (int r = 0; r < 4; ++r) acc[rf][c][r] *= alpha[r];

        // P -> per-wave LDS
#pragma unroll
        for (int c = 0; c < 2; ++c)
#pragma unroll
          for (int r = 0; r < 4; ++r)
            sP[w][rf * 16 + lg * 4 + r][c * 16 + lr] = (bf16_t)pv[rf][c][r];
      }

      // ---- PV: acc[rf] += P[rf](16x32) * V(32x192) ----
      bf16x8 pf[2];
#pragma unroll
      for (int rf = 0; rf < 2; ++rf)
        pf[rf] = *reinterpret_cast<const bf16x8*>(&sP[w][rf * 16 + lr][lg * 8]);
#pragma unroll
      for (int c2 = 0; c2 < 12; ++c2) {
        const int row = c2 * 16 + lr;
        bf16x8 vf = *reinterpret_cast<const bf16x8*>(
            &sV[cur][0] + row * KB32 + ((lg ^ (row & 3)) << 3));
        acc[0][c2] = __builtin_amdgcn_mfma_f32_16x16x32_bf16(pf[0], vf, acc[0][c2], 0, 0, 0);
        acc[1][c2] = __builtin_amdgcn_mfma_f32_16x16x32_bf16(pf[1], vf, acc[1][c2], 0, 0, 0);
      }
    }
    cur ^= 1;
  }

  // ---- epilogue ----
#pragma unroll
  for (int rf = 0; rf < 2; ++rf) {
    float rl[4];
#pragma unroll
    for (int r = 0; r < 4; ++r) rl[r] = 1.0f / lden[rf][r];
#pragma unroll
    for (int c2 = 0; c2 < 12; ++c2) {
#pragma unroll
      for (int r = 0; r < 4; ++r) {
        int i = wrow0 + rf * 16 + lg * 4 + r;
        size_t off = (size_t)(b * S_ + i) * QKD + h * DH_ + c2 * 16 + lr;
        attn[off] = (bf16_t)(acc[rf][c2][r] * rl[r]);
      }
    }
  }
}

// ---------------- launch ----------------
extern "C" void kernel_launch(void* const* d_in, const int* in_sizes, int n_in,
                              void* d_out, int out_size, void* d_ws, size_t ws_size,
                              hipStream_t stream) {
  const float* x        = (const float*)d_in[0];
  const float* w_qa     = (const float*)d_in[1];
  const float* q_norm_w = (const float*)d_in[2];
  const float* w_qb     = (const float*)d_in[3];
  const float* w_k      = (const float*)d_in[4];
  const float* w_v      = (const float*)d_in[5];
  const float* w_o      = (const float*)d_in[6];
  const float* attn_sink= (const float*)d_in[7];
  float* out = (float*)d_out;

  char* ws = (char*)d_ws;
  size_t off = 0;
  auto alloc = [&](size_t bytes) -> void* {
    void* p = ws + off;
    off += (bytes + 255) & ~(size_t)255;
    return p;
  };
  bf16_t* q_b  = (bf16_t*)alloc((size_t)NROWS * QKD * 2);
  bf16_t* k_b  = (bf16_t*)alloc((size_t)NROWS * DH_ * 2);
  bf16_t* vt_b = (bf16_t*)alloc((size_t)DH_ * NROWS * 2);
  bf16_t* wo_t = (bf16_t*)alloc((size_t)HID_ * QKD * 2);   // w_o^T [2048][3072]
  size_t temp_start = off;
  bf16_t* xb    = (bf16_t*)alloc((size_t)NROWS * HID_ * 2);
  bf16_t* wqa_t = (bf16_t*)alloc((size_t)QL_ * HID_ * 2);  // [512][2048]
  bf16_t* wqb_t = (bf16_t*)alloc((size_t)QKD * QL_ * 2);   // [3072][512]
  bf16_t* wk_t  = (bf16_t*)alloc((size_t)DH_ * HID_ * 2);  // [192][2048]
  bf16_t* wv_t  = (bf16_t*)alloc((size_t)DH_ * HID_ * 2);  // [192][2048]
  bf16_t* qa_b  = (bf16_t*)alloc((size_t)NROWS * QL_ * 2);
  bf16_t* attn_b = (bf16_t*)(ws + temp_start);             // overlays dead temps

  int n4x = (int)((size_t)NROWS * HID_ / 4);
  cast_f32_to_bf16<<<dim3((n4x + 255) / 256), dim3(256), 0, stream>>>(x, xb, n4x);
  transpose_cast<<<dim3(QL_ / 32, HID_ / 32), 256, 0, stream>>>(w_qa, wqa_t, HID_, QL_);
  transpose_cast<<<dim3(QKD / 32, QL_ / 32), 256, 0, stream>>>(w_qb, wqb_t, QL_, QKD);
  transpose_cast<<<dim3(DH_ / 32, HID_ / 32), 256, 0, stream>>>(w_k, wk_t, HID_, DH_);
  transpose_cast<<<dim3(DH_ / 32, HID_ / 32), 256, 0, stream>>>(w_v, wv_t, HID_, DH_);
  transpose_cast<<<dim3(HID_ / 32, QKD / 32), 256, 0, stream>>>(w_o, wo_t, QKD, HID_);

  gemm_kernel<1><<<dim3(QL_ / BN, NROWS / BM), 256, 0, stream>>>(xb, wqa_t, qa_b, NROWS, QL_, HID_);
  rmsnorm_kernel<<<dim3(NROWS), dim3(64), 0, stream>>>(qa_b, q_norm_w);
  gemm_kernel<1><<<dim3(QKD / BN, NROWS / BM), 256, 0, stream>>>(qa_b, wqb_t, q_b, NROWS, QKD, QL_);
  gemm_kernel<1><<<dim3(DH_ / BN, NROWS / BM), 256, 0, stream>>>(xb, wk_t, k_b, NROWS, DH_, HID_);
  gemm_kernel<2><<<dim3(DH_ / BN, NROWS / BM), 256, 0, stream>>>(xb, wv_t, vt_b, NROWS, DH_, HID_);
  rope_q_kernel<<<dim3((NROWS * H_ * 32) / 256), dim3(256), 0, stream>>>(q_b);
  rope_k_kernel<<<dim3((NROWS * 32) / 256), dim3(256), 0, stream>>>(k_b);
  attn_kernel<<<dim3(16 * 32), dim3(256), 0, stream>>>(q_b, k_b, vt_b, attn_sink, attn_b);
  gemm_kernel<0><<<dim3(HID_ / BN, NROWS / BM), 256, 0, stream>>>(attn_b, wo_t, out, NROWS, HID_, QKD);
}

// Round 5
// 437.571 us; speedup vs baseline: 3.0220x; 1.1222x over previous
//
#include <hip/hip_runtime.h>
#include <hip/hip_bf16.h>

typedef __bf16 bf16_t;
typedef __bf16 bf16x8 __attribute__((ext_vector_type(8)));
typedef __bf16 bf16x4 __attribute__((ext_vector_type(4)));
typedef float  f32x4  __attribute__((ext_vector_type(4)));
typedef __attribute__((address_space(3))) unsigned int lds_u32_t;
typedef __attribute__((address_space(1))) const unsigned int glb_u32_t;

#define B_    2
#define S_    2048
#define HID_  2048
#define H_    16
#define DH_   192
#define DR_   64
#define DN_   128
#define QL_   512
#define NROWS (B_*S_)          // 4096
#define QKD   (H_*DH_)         // 3072

#if __has_builtin(__builtin_amdgcn_exp2f)
#define EXP2(x) __builtin_amdgcn_exp2f(x)
#else
#define EXP2(x) exp2f(x)
#endif

// ---------------- cast f32 -> bf16 (vec4) ----------------
__global__ void cast_f32_to_bf16(const float* __restrict__ in, bf16_t* __restrict__ out, int n4) {
  int i = blockIdx.x * blockDim.x + threadIdx.x;
  if (i >= n4) return;
  const float4 v = reinterpret_cast<const float4*>(in)[i];
  bf16x4 r;
  r[0] = (bf16_t)v.x; r[1] = (bf16_t)v.y; r[2] = (bf16_t)v.z; r[3] = (bf16_t)v.w;
  reinterpret_cast<bf16x4*>(out)[i] = r;
}

// ---------------- transpose-cast f32 [R][C] -> bf16 [C][R] ----------------
__global__ __launch_bounds__(256) void transpose_cast(
    const float* __restrict__ in, bf16_t* __restrict__ out, int R, int Cc) {
  __shared__ float t[32][33];
  const int tx = threadIdx.x & 31;
  const int ty = threadIdx.x >> 5;       // 0..7
  const int r0 = blockIdx.y * 32, c0 = blockIdx.x * 32;
#pragma unroll
  for (int j = 0; j < 4; ++j)
    t[ty + j * 8][tx] = in[(size_t)(r0 + ty + j * 8) * Cc + c0 + tx];
  __syncthreads();
#pragma unroll
  for (int j = 0; j < 4; ++j)
    out[(size_t)(c0 + ty + j * 8) * R + r0 + tx] = (bf16_t)t[tx][ty + j * 8];
}

// ---------------- small bf16 MFMA GEMM (64x64 tile), B^T input ----------------
// C[M,N] = A[M,K] * BT[N,K]^T;  OMODE 1: bf16 C, 2: bf16 C^T (N x M)
#define BM 64
#define BN 64
#define BK 64
#define LDT 72

template<int OMODE>
__global__ __launch_bounds__(256) void gemm_kernel(
    const bf16_t* __restrict__ A, const bf16_t* __restrict__ BT,
    void* __restrict__ C, int M, int N, int K) {
  __shared__ __align__(16) bf16_t sA[BM][LDT];
  __shared__ __align__(16) bf16_t sB[BN][LDT];
  const int tid = threadIdx.x;
  const int w  = tid >> 6;
  const int l  = tid & 63;
  const int lg = l >> 4, lr = l & 15;
  const int m0 = blockIdx.y * BM, n0 = blockIdx.x * BN;

  f32x4 acc[4];
#pragma unroll
  for (int c = 0; c < 4; ++c) acc[c] = f32x4{0.f, 0.f, 0.f, 0.f};

  for (int k0 = 0; k0 < K; k0 += BK) {
#pragma unroll
    for (int i = 0; i < 2; ++i) {
      int cid = tid + i * 256;          // 0..511
      int row = cid >> 3;               // 0..63
      int cb  = (cid & 7) * 8;          // 0..56
      *reinterpret_cast<uint4*>(&sA[row][cb]) =
          *reinterpret_cast<const uint4*>(&A[(size_t)(m0 + row) * K + k0 + cb]);
      *reinterpret_cast<uint4*>(&sB[row][cb]) =
          *reinterpret_cast<const uint4*>(&BT[(size_t)(n0 + row) * K + k0 + cb]);
    }
    __syncthreads();
#pragma unroll
    for (int ks = 0; ks < 2; ++ks) {
      bf16x8 af = *reinterpret_cast<const bf16x8*>(&sA[w * 16 + lr][ks * 32 + lg * 8]);
#pragma unroll
      for (int c = 0; c < 4; ++c) {
        bf16x8 bfr = *reinterpret_cast<const bf16x8*>(&sB[c * 16 + lr][ks * 32 + lg * 8]);
        acc[c] = __builtin_amdgcn_mfma_f32_16x16x32_bf16(af, bfr, acc[c], 0, 0, 0);
      }
    }
    __syncthreads();
  }
#pragma unroll
  for (int c = 0; c < 4; ++c) {
#pragma unroll
    for (int r = 0; r < 4; ++r) {
      int row = m0 + w * 16 + lg * 4 + r;
      int col = n0 + c * 16 + lr;
      float v = acc[c][r];
      if (OMODE == 1)      ((bf16_t*)C)[(size_t)row * N + col] = (bf16_t)v;
      else                 ((bf16_t*)C)[(size_t)col * M + row] = (bf16_t)v;  // C^T
    }
  }
}

// ---------------- big bf16 MFMA GEMM (128x128x64 tile, m97 structure) --------
// C[M,N] = A[M,K] * BT[N,K]^T;  OMODE 0: f32 C, 1: bf16 C
// Staging via global_load_lds w=16, XOR chunk swizzle (8 chunks/row, ch^=row&7).
template<int OMODE>
__global__ __launch_bounds__(256) void gemm128_kernel(
    const bf16_t* __restrict__ A, const bf16_t* __restrict__ BT,
    void* __restrict__ C, int M, int N, int K) {
  __shared__ __align__(16) bf16_t sA[128 * 64];   // 16KB, swizzled chunks
  __shared__ __align__(16) bf16_t sB[128 * 64];   // 16KB
  const int tid = threadIdx.x;
  const int w  = tid >> 6;
  const int l  = tid & 63;
  const int lg = l >> 4, lr = l & 15;
  const int wm = w >> 1, wn = w & 1;              // 2x2 waves, 64x64 each
  const int m0 = blockIdx.y * 128, n0 = blockIdx.x * 128;

  // per-thread staging offsets: 4 chunks for A, 4 for B
  size_t aoff[4], boff[4];
  int ldsoff[4];
#pragma unroll
  for (int i = 0; i < 4; ++i) {
    int cid = i * 256 + tid;            // 0..1023
    int row = cid >> 3, ch = cid & 7;
    int sch = ch ^ (row & 7);
    aoff[i] = (size_t)(m0 + row) * K + sch * 8;
    boff[i] = (size_t)(n0 + row) * K + sch * 8;
    ldsoff[i] = (i * 256 + w * 64) * 8; // wave-uniform base + lane*8 elems
  }

  f32x4 acc[4][4];
#pragma unroll
  for (int mi = 0; mi < 4; ++mi)
#pragma unroll
    for (int ni = 0; ni < 4; ++ni) acc[mi][ni] = f32x4{0.f, 0.f, 0.f, 0.f};

  for (int k0 = 0; k0 < K; k0 += 64) {
#pragma unroll
    for (int i = 0; i < 4; ++i) {
      __builtin_amdgcn_global_load_lds((glb_u32_t*)(A + aoff[i] + k0),
                                       (lds_u32_t*)(sA + ldsoff[i]), 16, 0, 0);
      __builtin_amdgcn_global_load_lds((glb_u32_t*)(BT + boff[i] + k0),
                                       (lds_u32_t*)(sB + ldsoff[i]), 16, 0, 0);
    }
    asm volatile("s_waitcnt vmcnt(0)" ::: "memory");
    __syncthreads();

#pragma unroll
    for (int ks = 0; ks < 2; ++ks) {
      bf16x8 af[4], bfr[4];
#pragma unroll
      for (int mi = 0; mi < 4; ++mi) {
        int row = wm * 64 + mi * 16 + lr;
        af[mi] = *reinterpret_cast<const bf16x8*>(
            sA + row * 64 + (((ks * 4 + lg) ^ (row & 7)) << 3));
      }
#pragma unroll
      for (int ni = 0; ni < 4; ++ni) {
        int row = wn * 64 + ni * 16 + lr;
        bfr[ni] = *reinterpret_cast<const bf16x8*>(
            sB + row * 64 + (((ks * 4 + lg) ^ (row & 7)) << 3));
      }
#pragma unroll
      for (int mi = 0; mi < 4; ++mi)
#pragma unroll
        for (int ni = 0; ni < 4; ++ni)
          acc[mi][ni] = __builtin_amdgcn_mfma_f32_16x16x32_bf16(af[mi], bfr[ni], acc[mi][ni], 0, 0, 0);
    }
    __syncthreads();
  }

#pragma unroll
  for (int mi = 0; mi < 4; ++mi) {
#pragma unroll
    for (int ni = 0; ni < 4; ++ni) {
#pragma unroll
      for (int r = 0; r < 4; ++r) {
        int row = m0 + wm * 64 + mi * 16 + lg * 4 + r;
        int col = n0 + wn * 64 + ni * 16 + lr;
        float v = acc[mi][ni][r];
        if (OMODE == 0) ((float*)C)[(size_t)row * N + col]  = v;
        else            ((bf16_t*)C)[(size_t)row * N + col] = (bf16_t)v;
      }
    }
  }
}

// ---------------- RMSNorm (in-place, one wave per row of 512) ----------------
__global__ __launch_bounds__(64) void rmsnorm_kernel(bf16_t* __restrict__ qa,
                                                     const float* __restrict__ wnorm) {
  int row = blockIdx.x;
  int l = threadIdx.x;
  bf16x8 v = *reinterpret_cast<const bf16x8*>(&qa[(size_t)row * QL_ + l * 8]);
  float f[8];
  float ss = 0.f;
#pragma unroll
  for (int e = 0; e < 8; ++e) { f[e] = (float)v[e]; ss += f[e] * f[e]; }
#pragma unroll
  for (int off = 32; off >= 1; off >>= 1) ss += __shfl_xor(ss, off);
  float rstd = rsqrtf(ss * (1.0f / 512.0f) + 1e-6f);
  bf16x8 o;
#pragma unroll
  for (int e = 0; e < 8; ++e) o[e] = (bf16_t)(f[e] * rstd * wnorm[l * 8 + e]);
  *reinterpret_cast<bf16x8*>(&qa[(size_t)row * QL_ + l * 8]) = o;
}

// ---------------- RoPE ----------------
__global__ void rope_q_kernel(bf16_t* __restrict__ q) {
  int idx = blockIdx.x * blockDim.x + threadIdx.x;  // NROWS*16*32
  int d   = idx & 31;
  int h   = (idx >> 5) & 15;
  int row = idx >> 9;
  if (row >= NROWS) return;
  int s = row & (S_ - 1);
  float freq = (float)s * expf(-(float)d * (9.210340371976184f / 32.0f));
  float sn, cs;
  sincosf(freq, &sn, &cs);
  size_t base = (size_t)row * QKD + h * DH_ + DN_ + d;
  float q1 = (float)q[base], q2 = (float)q[base + 32];
  q[base]      = (bf16_t)(q1 * cs - q2 * sn);
  q[base + 32] = (bf16_t)(q2 * cs + q1 * sn);
}

__global__ void rope_k_kernel(bf16_t* __restrict__ k) {
  int idx = blockIdx.x * blockDim.x + threadIdx.x;  // NROWS*32
  int d   = idx & 31;
  int row = idx >> 5;
  if (row >= NROWS) return;
  int s = row & (S_ - 1);
  float freq = (float)s * expf(-(float)d * (9.210340371976184f / 32.0f));
  float sn, cs;
  sincosf(freq, &sn, &cs);
  size_t base = (size_t)row * DH_ + DN_ + d;
  float k1 = (float)k[base], k2 = (float)k[base + 32];
  k[base]      = (bf16_t)(k1 * cs - k2 * sn);
  k[base + 32] = (bf16_t)(k2 * cs + k1 * sn);
}

// ---------------- causal flash attention with sink ----------------
#define KB32  32
#define SPLD  40

__global__ __launch_bounds__(256, 2) void attn_kernel(
    const bf16_t* __restrict__ q, const bf16_t* __restrict__ k,
    const bf16_t* __restrict__ vt, const float* __restrict__ sink,
    bf16_t* __restrict__ attn) {
  __shared__ __align__(16) bf16_t sK[2][KB32 * DH_];
  __shared__ __align__(16) bf16_t sV[2][DH_ * KB32];
  __shared__ __align__(16) bf16_t sP[4][32][SPLD];
  const int tid = threadIdx.x;
  const int w  = tid >> 6;
  const int l  = tid & 63;
  const int lg = l >> 4, lr = l & 15;
  const int x  = blockIdx.x;
  const int qt = x >> 5;
  const int bh = x & 31;
  const int b  = bh >> 4, h = bh & 15;
  const int wrow0 = qt * 128 + w * 32;
  const int ktmax_w = 4 * qt + w;
  const int ktmax_b = 4 * qt + 3;

  const bf16_t* kb = k + (size_t)(b * S_) * DH_;

  int koff[3], voff[3], ldst[3];
#pragma unroll
  for (int i = 0; i < 3; ++i) {
    int g = i * 256 + tid;
    int krow = g / 24, kch = g - krow * 24;
    koff[i] = krow * DH_ + ((kch ^ (krow & 7)) << 3);
    int vrow = g >> 2, vch = g & 3;
    voff[i] = vrow * NROWS + ((vch ^ (vrow & 3)) << 3);
    ldst[i] = (i * 256 + w * 64) * 8;
  }

  auto stage = [&](int kt, int bu) {
    const bf16_t* ksrc = kb + (size_t)kt * KB32 * DH_;
    const bf16_t* vsrc = vt + (size_t)(b * S_ + kt * KB32);
#pragma unroll
    for (int i = 0; i < 3; ++i) {
      __builtin_amdgcn_global_load_lds((glb_u32_t*)(ksrc + koff[i]),
                                       (lds_u32_t*)(&sK[bu][0] + ldst[i]), 16, 0, 0);
      __builtin_amdgcn_global_load_lds((glb_u32_t*)(vsrc + voff[i]),
                                       (lds_u32_t*)(&sV[bu][0] + ldst[i]), 16, 0, 0);
    }
  };

  bf16x8 qf[2][6];
#pragma unroll
  for (int rf = 0; rf < 2; ++rf) {
    size_t rowoff = (size_t)(b * S_ + wrow0 + rf * 16 + lr) * QKD + h * DH_;
#pragma unroll
    for (int ks = 0; ks < 6; ++ks)
      qf[rf][ks] = *reinterpret_cast<const bf16x8*>(&q[rowoff + ks * 32 + lg * 8]);
  }

  f32x4 acc[2][12];
#pragma unroll
  for (int rf = 0; rf < 2; ++rf)
#pragma unroll
    for (int c = 0; c < 12; ++c) acc[rf][c] = f32x4{0.f, 0.f, 0.f, 0.f};

  const float L2E = 1.4426950408889634f;
  float m[2][4], lden[2][4];
  float sk2 = sink[h] * L2E;
#pragma unroll
  for (int rf = 0; rf < 2; ++rf)
#pragma unroll
    for (int r = 0; r < 4; ++r) { m[rf][r] = sk2; lden[rf][r] = 1.0f; }

  const float scale2 = 0.10411754646447386f;  // 192^-0.5 * log2(e)

  stage(0, 0);
  int cur = 0;

  for (int kt = 0; kt <= ktmax_b; ++kt) {
    asm volatile("s_waitcnt vmcnt(0)" ::: "memory");
    __syncthreads();

    if (kt < ktmax_b) stage(kt + 1, cur ^ 1);

    const bool active = (kt <= ktmax_w);
    if (active) {
      f32x4 sc[2][2];
#pragma unroll
      for (int rf = 0; rf < 2; ++rf)
#pragma unroll
        for (int c = 0; c < 2; ++c) sc[rf][c] = f32x4{0.f, 0.f, 0.f, 0.f};
#pragma unroll
      for (int c = 0; c < 2; ++c) {
        const int row = c * 16 + lr;
        const int rx  = row & 7;
        const bf16_t* kr = &sK[cur][0] + row * DH_;
#pragma unroll
        for (int ks = 0; ks < 6; ++ks) {
          bf16x8 kf = *reinterpret_cast<const bf16x8*>(kr + (((ks * 4 + lg) ^ rx) << 3));
          sc[0][c] = __builtin_amdgcn_mfma_f32_16x16x32_bf16(qf[0][ks], kf, sc[0][c], 0, 0, 0);
          sc[1][c] = __builtin_amdgcn_mfma_f32_16x16x32_bf16(qf[1][ks], kf, sc[1][c], 0, 0, 0);
        }
      }

      float pv[2][2][4];
      const bool diag = (kt == ktmax_w);
#pragma unroll
      for (int rf = 0; rf < 2; ++rf)
#pragma unroll
        for (int c = 0; c < 2; ++c)
#pragma unroll
          for (int r = 0; r < 4; ++r) {
            float s = sc[rf][c][r] * scale2;
            if (diag && (c * 16 + lr) > (rf * 16 + lg * 4 + r)) s = -1e30f;
            pv[rf][c][r] = s;
          }

#pragma unroll
      for (int rf = 0; rf < 2; ++rf) {
        float rmax[4], alpha[4], psum[4];
#pragma unroll
        for (int r = 0; r < 4; ++r) rmax[r] = fmaxf(pv[rf][0][r], pv[rf][1][r]);
#pragma unroll
        for (int off = 1; off < 16; off <<= 1) {
#pragma unroll
          for (int r = 0; r < 4; ++r) rmax[r] = fmaxf(rmax[r], __shfl_xor(rmax[r], off));
        }
#pragma unroll
        for (int r = 0; r < 4; ++r) {
          float mn = fmaxf(m[rf][r], rmax[r]);
          alpha[r] = EXP2(m[rf][r] - mn);
          m[rf][r] = mn;
          psum[r] = 0.f;
        }
#pragma unroll
        for (int c = 0; c < 2; ++c)
#pragma unroll
          for (int r = 0; r < 4; ++r) {
            float p = EXP2(pv[rf][c][r] - m[rf][r]);
            pv[rf][c][r] = p;
            psum[r] += p;
          }
#pragma unroll
        for (int off = 1; off < 16; off <<= 1) {
#pragma unroll
          for (int r = 0; r < 4; ++r) psum[r] += __shfl_xor(psum[r], off);
        }
#pragma unroll
        for (int r = 0; r < 4; ++r) lden[rf][r] = lden[rf][r] * alpha[r] + psum[r];
#pragma unroll
        for (int c = 0; c < 12; ++c)
#pragma unroll
          for (int r = 0; r < 4; ++r) acc[rf][c][r] *= alpha[r];

#pragma unroll
        for (int c = 0; c < 2; ++c)
#pragma unroll
          for (int r = 0; r < 4; ++r)
            sP[w][rf * 16 + lg * 4 + r][c * 16 + lr] = (bf16_t)pv[rf][c][r];
      }

      bf16x8 pf[2];
#pragma unroll
      for (int rf = 0; rf < 2; ++rf)
        pf[rf] = *reinterpret_cast<const bf16x8*>(&sP[w][rf * 16 + lr][lg * 8]);
#pragma unroll
      for (int c2 = 0; c2 < 12; ++c2) {
        const int row = c2 * 16 + lr;
        bf16x8 vf = *reinterpret_cast<const bf16x8*>(
            &sV[cur][0] + row * KB32 + ((lg ^ (row & 3)) << 3));
        acc[0][c2] = __builtin_amdgcn_mfma_f32_16x16x32_bf16(pf[0], vf, acc[0][c2], 0, 0, 0);
        acc[1][c2] = __builtin_amdgcn_mfma_f32_16x16x32_bf16(pf[1], vf, acc[1][c2], 0, 0, 0);
      }
    }
    cur ^= 1;
  }

#pragma unroll
  for (int rf = 0; rf < 2; ++rf) {
    float rl[4];
#pragma unroll
    for (int r = 0; r < 4; ++r) rl[r] = 1.0f / lden[rf][r];
#pragma unroll
    for (int c2 = 0; c2 < 12; ++c2) {
#pragma unroll
      for (int r = 0; r < 4; ++r) {
        int i = wrow0 + rf * 16 + lg * 4 + r;
        size_t off = (size_t)(b * S_ + i) * QKD + h * DH_ + c2 * 16 + lr;
        attn[off] = (bf16_t)(acc[rf][c2][r] * rl[r]);
      }
    }
  }
}

// ---------------- launch ----------------
extern "C" void kernel_launch(void* const* d_in, const int* in_sizes, int n_in,
                              void* d_out, int out_size, void* d_ws, size_t ws_size,
                              hipStream_t stream) {
  const float* x        = (const float*)d_in[0];
  const float* w_qa     = (const float*)d_in[1];
  const float* q_norm_w = (const float*)d_in[2];
  const float* w_qb     = (const float*)d_in[3];
  const float* w_k      = (const float*)d_in[4];
  const float* w_v      = (const float*)d_in[5];
  const float* w_o      = (const float*)d_in[6];
  const float* attn_sink= (const float*)d_in[7];
  float* out = (float*)d_out;

  char* ws = (char*)d_ws;
  size_t off = 0;
  auto alloc = [&](size_t bytes) -> void* {
    void* p = ws + off;
    off += (bytes + 255) & ~(size_t)255;
    return p;
  };
  bf16_t* q_b  = (bf16_t*)alloc((size_t)NROWS * QKD * 2);
  bf16_t* k_b  = (bf16_t*)alloc((size_t)NROWS * DH_ * 2);
  bf16_t* vt_b = (bf16_t*)alloc((size_t)DH_ * NROWS * 2);
  bf16_t* wo_t = (bf16_t*)alloc((size_t)HID_ * QKD * 2);   // w_o^T [2048][3072]
  size_t temp_start = off;
  bf16_t* xb    = (bf16_t*)alloc((size_t)NROWS * HID_ * 2);
  bf16_t* wqa_t = (bf16_t*)alloc((size_t)QL_ * HID_ * 2);  // [512][2048]
  bf16_t* wqb_t = (bf16_t*)alloc((size_t)QKD * QL_ * 2);   // [3072][512]
  bf16_t* wk_t  = (bf16_t*)alloc((size_t)DH_ * HID_ * 2);  // [192][2048]
  bf16_t* wv_t  = (bf16_t*)alloc((size_t)DH_ * HID_ * 2);  // [192][2048]
  bf16_t* qa_b  = (bf16_t*)alloc((size_t)NROWS * QL_ * 2);
  bf16_t* attn_b = (bf16_t*)(ws + temp_start);             // overlays dead temps

  int n4x = (int)((size_t)NROWS * HID_ / 4);
  cast_f32_to_bf16<<<dim3((n4x + 255) / 256), dim3(256), 0, stream>>>(x, xb, n4x);
  transpose_cast<<<dim3(QL_ / 32, HID_ / 32), 256, 0, stream>>>(w_qa, wqa_t, HID_, QL_);
  transpose_cast<<<dim3(QKD / 32, QL_ / 32), 256, 0, stream>>>(w_qb, wqb_t, QL_, QKD);
  transpose_cast<<<dim3(DH_ / 32, HID_ / 32), 256, 0, stream>>>(w_k, wk_t, HID_, DH_);
  transpose_cast<<<dim3(DH_ / 32, HID_ / 32), 256, 0, stream>>>(w_v, wv_t, HID_, DH_);
  transpose_cast<<<dim3(HID_ / 32, QKD / 32), 256, 0, stream>>>(w_o, wo_t, QKD, HID_);

  // q_a = rmsnorm(x @ w_qa)   [128-tile GEMM]
  gemm128_kernel<1><<<dim3(QL_ / 128, NROWS / 128), 256, 0, stream>>>(xb, wqa_t, qa_b, NROWS, QL_, HID_);
  rmsnorm_kernel<<<dim3(NROWS), dim3(64), 0, stream>>>(qa_b, q_norm_w);
  // q = q_a @ w_qb            [128-tile GEMM]
  gemm128_kernel<1><<<dim3(QKD / 128, NROWS / 128), 256, 0, stream>>>(qa_b, wqb_t, q_b, NROWS, QKD, QL_);
  // k, v^T                    [64-tile GEMM, N=192]
  gemm_kernel<1><<<dim3(DH_ / BN, NROWS / BM), 256, 0, stream>>>(xb, wk_t, k_b, NROWS, DH_, HID_);
  gemm_kernel<2><<<dim3(DH_ / BN, NROWS / BM), 256, 0, stream>>>(xb, wv_t, vt_b, NROWS, DH_, HID_);
  rope_q_kernel<<<dim3((NROWS * H_ * 32) / 256), dim3(256), 0, stream>>>(q_b);
  rope_k_kernel<<<dim3((NROWS * 32) / 256), dim3(256), 0, stream>>>(k_b);
  attn_kernel<<<dim3(16 * 32), dim3(256), 0, stream>>>(q_b, k_b, vt_b, attn_sink, attn_b);
  // out = attn @ w_o          [128-tile GEMM, f32 out]
  gemm128_kernel<0><<<dim3(HID_ / 128, NROWS / 128), 256, 0, stream>>>(attn_b, wo_t, out, NROWS, HID_, QKD);
}

// Round 6
// 325.204 us; speedup vs baseline: 4.0661x; 1.3455x over previous
//
#include <hip/hip_runtime.h>
#include <hip/hip_bf16.h>

typedef __bf16 bf16_t;
typedef __bf16 bf16x8 __attribute__((ext_vector_type(8)));
typedef __bf16 bf16x4 __attribute__((ext_vector_type(4)));
typedef float  f32x4  __attribute__((ext_vector_type(4)));
typedef __attribute__((address_space(3))) unsigned int lds_u32_t;
typedef __attribute__((address_space(1))) const unsigned int glb_u32_t;

#define B_    2
#define S_    2048
#define HID_  2048
#define H_    16
#define DH_   192
#define DR_   64
#define DN_   128
#define QL_   512
#define NROWS (B_*S_)          // 4096
#define QKD   (H_*DH_)         // 3072

#if __has_builtin(__builtin_amdgcn_exp2f)
#define EXP2(x) __builtin_amdgcn_exp2f(x)
#else
#define EXP2(x) exp2f(x)
#endif

// ---------------- cast f32 -> bf16 (vec4) ----------------
__global__ void cast_f32_to_bf16(const float* __restrict__ in, bf16_t* __restrict__ out, int n4) {
  int i = blockIdx.x * blockDim.x + threadIdx.x;
  if (i >= n4) return;
  const float4 v = reinterpret_cast<const float4*>(in)[i];
  bf16x4 r;
  r[0] = (bf16_t)v.x; r[1] = (bf16_t)v.y; r[2] = (bf16_t)v.z; r[3] = (bf16_t)v.w;
  reinterpret_cast<bf16x4*>(out)[i] = r;
}

// ---------------- transpose-cast f32 [R][C] -> bf16 [C][R] ----------------
__global__ __launch_bounds__(256) void transpose_cast(
    const float* __restrict__ in, bf16_t* __restrict__ out, int R, int Cc) {
  __shared__ float t[32][33];
  const int tx = threadIdx.x & 31;
  const int ty = threadIdx.x >> 5;       // 0..7
  const int r0 = blockIdx.y * 32, c0 = blockIdx.x * 32;
#pragma unroll
  for (int j = 0; j < 4; ++j)
    t[ty + j * 8][tx] = in[(size_t)(r0 + ty + j * 8) * Cc + c0 + tx];
  __syncthreads();
#pragma unroll
  for (int j = 0; j < 4; ++j)
    out[(size_t)(c0 + ty + j * 8) * R + r0 + tx] = (bf16_t)t[tx][ty + j * 8];
}

// ---------------- merged K/V GEMM (64x64 tile), B^T input ----------------
// A[4096][2048] * wkv^T -> cols 0..191: k_b row-major; cols 192..383: vt (transposed)
#define BM 64
#define BN 64
#define BK 64
#define LDT 72

__global__ __launch_bounds__(256) void gemm_kv_kernel(
    const bf16_t* __restrict__ A, const bf16_t* __restrict__ BT,
    bf16_t* __restrict__ Kout, bf16_t* __restrict__ VTout) {
  __shared__ __align__(16) bf16_t sA[BM][LDT];
  __shared__ __align__(16) bf16_t sB[BN][LDT];
  const int tid = threadIdx.x;
  const int w  = tid >> 6;
  const int l  = tid & 63;
  const int lg = l >> 4, lr = l & 15;
  const int m0 = blockIdx.y * BM, n0 = blockIdx.x * BN;
  const int K = HID_;

  f32x4 acc[4];
#pragma unroll
  for (int c = 0; c < 4; ++c) acc[c] = f32x4{0.f, 0.f, 0.f, 0.f};

  for (int k0 = 0; k0 < K; k0 += BK) {
#pragma unroll
    for (int i = 0; i < 2; ++i) {
      int cid = tid + i * 256;
      int row = cid >> 3;
      int cb  = (cid & 7) * 8;
      *reinterpret_cast<uint4*>(&sA[row][cb]) =
          *reinterpret_cast<const uint4*>(&A[(size_t)(m0 + row) * K + k0 + cb]);
      *reinterpret_cast<uint4*>(&sB[row][cb]) =
          *reinterpret_cast<const uint4*>(&BT[(size_t)(n0 + row) * K + k0 + cb]);
    }
    __syncthreads();
#pragma unroll
    for (int ks = 0; ks < 2; ++ks) {
      bf16x8 af = *reinterpret_cast<const bf16x8*>(&sA[w * 16 + lr][ks * 32 + lg * 8]);
#pragma unroll
      for (int c = 0; c < 4; ++c) {
        bf16x8 bfr = *reinterpret_cast<const bf16x8*>(&sB[c * 16 + lr][ks * 32 + lg * 8]);
        acc[c] = __builtin_amdgcn_mfma_f32_16x16x32_bf16(af, bfr, acc[c], 0, 0, 0);
      }
    }
    __syncthreads();
  }
#pragma unroll
  for (int c = 0; c < 4; ++c) {
#pragma unroll
    for (int r = 0; r < 4; ++r) {
      int row = m0 + w * 16 + lg * 4 + r;
      int col = n0 + c * 16 + lr;
      float v = acc[c][r];
      if (col < DH_) Kout[(size_t)row * DH_ + col] = (bf16_t)v;
      else           VTout[(size_t)(col - DH_) * NROWS + row] = (bf16_t)v;
    }
  }
}

// ---------------- big bf16 MFMA GEMM (128x128x64 tile, m97 structure) --------
// C[M,N] = A[M,K] * BT[N,K]^T;  OMODE 0: f32 C, 1: bf16 C
template<int OMODE>
__global__ __launch_bounds__(256) void gemm128_kernel(
    const bf16_t* __restrict__ A, const bf16_t* __restrict__ BT,
    void* __restrict__ C, int M, int N, int K) {
  __shared__ __align__(16) bf16_t sA[128 * 64];
  __shared__ __align__(16) bf16_t sB[128 * 64];
  const int tid = threadIdx.x;
  const int w  = tid >> 6;
  const int l  = tid & 63;
  const int lg = l >> 4, lr = l & 15;
  const int wm = w >> 1, wn = w & 1;
  const int m0 = blockIdx.y * 128, n0 = blockIdx.x * 128;

  size_t aoff[4], boff[4];
  int ldsoff[4];
#pragma unroll
  for (int i = 0; i < 4; ++i) {
    int cid = i * 256 + tid;
    int row = cid >> 3, ch = cid & 7;
    int sch = ch ^ (row & 7);
    aoff[i] = (size_t)(m0 + row) * K + sch * 8;
    boff[i] = (size_t)(n0 + row) * K + sch * 8;
    ldsoff[i] = (i * 256 + w * 64) * 8;
  }

  f32x4 acc[4][4];
#pragma unroll
  for (int mi = 0; mi < 4; ++mi)
#pragma unroll
    for (int ni = 0; ni < 4; ++ni) acc[mi][ni] = f32x4{0.f, 0.f, 0.f, 0.f};

  for (int k0 = 0; k0 < K; k0 += 64) {
#pragma unroll
    for (int i = 0; i < 4; ++i) {
      __builtin_amdgcn_global_load_lds((glb_u32_t*)(A + aoff[i] + k0),
                                       (lds_u32_t*)(sA + ldsoff[i]), 16, 0, 0);
      __builtin_amdgcn_global_load_lds((glb_u32_t*)(BT + boff[i] + k0),
                                       (lds_u32_t*)(sB + ldsoff[i]), 16, 0, 0);
    }
    asm volatile("s_waitcnt vmcnt(0)" ::: "memory");
    __syncthreads();

#pragma unroll
    for (int ks = 0; ks < 2; ++ks) {
      bf16x8 af[4], bfr[4];
#pragma unroll
      for (int mi = 0; mi < 4; ++mi) {
        int row = wm * 64 + mi * 16 + lr;
        af[mi] = *reinterpret_cast<const bf16x8*>(
            sA + row * 64 + (((ks * 4 + lg) ^ (row & 7)) << 3));
      }
#pragma unroll
      for (int ni = 0; ni < 4; ++ni) {
        int row = wn * 64 + ni * 16 + lr;
        bfr[ni] = *reinterpret_cast<const bf16x8*>(
            sB + row * 64 + (((ks * 4 + lg) ^ (row & 7)) << 3));
      }
#pragma unroll
      for (int mi = 0; mi < 4; ++mi)
#pragma unroll
        for (int ni = 0; ni < 4; ++ni)
          acc[mi][ni] = __builtin_amdgcn_mfma_f32_16x16x32_bf16(af[mi], bfr[ni], acc[mi][ni], 0, 0, 0);
    }
    __syncthreads();
  }

#pragma unroll
  for (int mi = 0; mi < 4; ++mi) {
#pragma unroll
    for (int ni = 0; ni < 4; ++ni) {
#pragma unroll
      for (int r = 0; r < 4; ++r) {
        int row = m0 + wm * 64 + mi * 16 + lg * 4 + r;
        int col = n0 + wn * 64 + ni * 16 + lr;
        float v = acc[mi][ni][r];
        if (OMODE == 0) ((float*)C)[(size_t)row * N + col]  = v;
        else            ((bf16_t*)C)[(size_t)row * N + col] = (bf16_t)v;
      }
    }
  }
}

// ---------------- RMSNorm (in-place, one wave per row of 512) ----------------
__global__ __launch_bounds__(64) void rmsnorm_kernel(bf16_t* __restrict__ qa,
                                                     const float* __restrict__ wnorm) {
  int row = blockIdx.x;
  int l = threadIdx.x;
  bf16x8 v = *reinterpret_cast<const bf16x8*>(&qa[(size_t)row * QL_ + l * 8]);
  float f[8];
  float ss = 0.f;
#pragma unroll
  for (int e = 0; e < 8; ++e) { f[e] = (float)v[e]; ss += f[e] * f[e]; }
#pragma unroll
  for (int off = 32; off >= 1; off >>= 1) ss += __shfl_xor(ss, off);
  float rstd = rsqrtf(ss * (1.0f / 512.0f) + 1e-6f);
  bf16x8 o;
#pragma unroll
  for (int e = 0; e < 8; ++e) o[e] = (bf16_t)(f[e] * rstd * wnorm[l * 8 + e]);
  *reinterpret_cast<bf16x8*>(&qa[(size_t)row * QL_ + l * 8]) = o;
}

// ---------------- RoPE ----------------
__global__ void rope_q_kernel(bf16_t* __restrict__ q) {
  int idx = blockIdx.x * blockDim.x + threadIdx.x;  // NROWS*16*32
  int d   = idx & 31;
  int h   = (idx >> 5) & 15;
  int row = idx >> 9;
  if (row >= NROWS) return;
  int s = row & (S_ - 1);
  float freq = (float)s * expf(-(float)d * (9.210340371976184f / 32.0f));
  float sn, cs;
  sincosf(freq, &sn, &cs);
  size_t base = (size_t)row * QKD + h * DH_ + DN_ + d;
  float q1 = (float)q[base], q2 = (float)q[base + 32];
  q[base]      = (bf16_t)(q1 * cs - q2 * sn);
  q[base + 32] = (bf16_t)(q2 * cs + q1 * sn);
}

__global__ void rope_k_kernel(bf16_t* __restrict__ k) {
  int idx = blockIdx.x * blockDim.x + threadIdx.x;  // NROWS*32
  int d   = idx & 31;
  int row = idx >> 5;
  if (row >= NROWS) return;
  int s = row & (S_ - 1);
  float freq = (float)s * expf(-(float)d * (9.210340371976184f / 32.0f));
  float sn, cs;
  sincosf(freq, &sn, &cs);
  size_t base = (size_t)row * DH_ + DN_ + d;
  float k1 = (float)k[base], k2 = (float)k[base + 32];
  k[base]      = (bf16_t)(k1 * cs - k2 * sn);
  k[base + 32] = (bf16_t)(k2 * cs + k1 * sn);
}

// ---------------- causal flash attention with sink ----------------
// Denominator computed by MFMA via a constant "ones" B-fragment (13th col-tile
// of acc). Defer-max (THR=8 in log2 domain): m stays fixed unless a row's tile
// max exceeds m+8 (checked with one __all, no shuffles); slow path rescales.
#define KB32  32
#define SPLD  40

__global__ __launch_bounds__(256, 2) void attn_kernel(
    const bf16_t* __restrict__ q, const bf16_t* __restrict__ k,
    const bf16_t* __restrict__ vt, const float* __restrict__ sink,
    bf16_t* __restrict__ attn) {
  __shared__ __align__(16) bf16_t sK[2][KB32 * DH_];
  __shared__ __align__(16) bf16_t sV[2][DH_ * KB32];
  __shared__ __align__(16) bf16_t sP[4][32][SPLD];
  const int tid = threadIdx.x;
  const int w  = tid >> 6;
  const int l  = tid & 63;
  const int lg = l >> 4, lr = l & 15;
  const int qx = blockIdx.x >> 5;
  const int qt = (qx < 8) ? (15 - qx) : (qx - 8);  // heavy first; x,x+256 pair to const work
  const int bh = blockIdx.x & 31;
  const int b  = bh >> 4, h = bh & 15;
  const int wrow0 = qt * 128 + w * 32;
  const int ktmax_w = 4 * qt + w;
  const int ktmax_b = 4 * qt + 3;

  const bf16_t* kb = k + (size_t)(b * S_) * DH_;

  int koff[3], voff[3], ldst[3];
#pragma unroll
  for (int i = 0; i < 3; ++i) {
    int g = i * 256 + tid;
    int krow = g / 24, kch = g - krow * 24;
    koff[i] = krow * DH_ + ((kch ^ (krow & 7)) << 3);
    int vrow = g >> 2, vch = g & 3;
    voff[i] = vrow * NROWS + ((vch ^ (vrow & 3)) << 3);
    ldst[i] = (i * 256 + w * 64) * 8;
  }

  auto stage = [&](int kt, int bu) {
    const bf16_t* ksrc = kb + (size_t)kt * KB32 * DH_;
    const bf16_t* vsrc = vt + (size_t)(b * S_ + kt * KB32);
#pragma unroll
    for (int i = 0; i < 3; ++i) {
      __builtin_amdgcn_global_load_lds((glb_u32_t*)(ksrc + koff[i]),
                                       (lds_u32_t*)(&sK[bu][0] + ldst[i]), 16, 0, 0);
      __builtin_amdgcn_global_load_lds((glb_u32_t*)(vsrc + voff[i]),
                                       (lds_u32_t*)(&sV[bu][0] + ldst[i]), 16, 0, 0);
    }
  };

  bf16x8 qf[2][6];
#pragma unroll
  for (int rf = 0; rf < 2; ++rf) {
    size_t rowoff = (size_t)(b * S_ + wrow0 + rf * 16 + lr) * QKD + h * DH_;
#pragma unroll
    for (int ks = 0; ks < 6; ++ks)
      qf[rf][ks] = *reinterpret_cast<const bf16x8*>(&q[rowoff + ks * 32 + lg * 8]);
  }

  // constant "ones" B-fragment: B[col=192][k]=1 lives in lanes lr==0
  bf16x8 vones;
#pragma unroll
  for (int e = 0; e < 8; ++e) vones[e] = (bf16_t)((lr == 0) ? 1.0f : 0.0f);

  // acc[rf][0..11]: output cols; acc[rf][12]: softmax denominator column
  f32x4 acc[2][13];
#pragma unroll
  for (int rf = 0; rf < 2; ++rf) {
#pragma unroll
    for (int c = 0; c < 12; ++c) acc[rf][c] = f32x4{0.f, 0.f, 0.f, 0.f};
    float init = (lr == 0) ? 1.0f : 0.0f;   // sink: exp2(sk2 - m0) = 1
    acc[rf][12] = f32x4{init, init, init, init};
  }

  const float L2E = 1.4426950408889634f;
  float m[2][4];
  float sk2 = sink[h] * L2E;
#pragma unroll
  for (int rf = 0; rf < 2; ++rf)
#pragma unroll
    for (int r = 0; r < 4; ++r) m[rf][r] = sk2;

  const float scale2 = 0.10411754646447386f;  // 192^-0.5 * log2(e)

  stage(0, 0);
  int cur = 0;

  for (int kt = 0; kt <= ktmax_b; ++kt) {
    asm volatile("s_waitcnt vmcnt(0)" ::: "memory");
    __syncthreads();

    if (kt < ktmax_b) stage(kt + 1, cur ^ 1);

    if (kt <= ktmax_w) {
      // ---- QK^T ----
      f32x4 sc[2][2];
#pragma unroll
      for (int rf = 0; rf < 2; ++rf)
#pragma unroll
        for (int c = 0; c < 2; ++c) sc[rf][c] = f32x4{0.f, 0.f, 0.f, 0.f};
#pragma unroll
      for (int c = 0; c < 2; ++c) {
        const int row = c * 16 + lr;
        const int rx  = row & 7;
        const bf16_t* kr = &sK[cur][0] + row * DH_;
#pragma unroll
        for (int ks = 0; ks < 6; ++ks) {
          bf16x8 kf = *reinterpret_cast<const bf16x8*>(kr + (((ks * 4 + lg) ^ rx) << 3));
          sc[0][c] = __builtin_amdgcn_mfma_f32_16x16x32_bf16(qf[0][ks], kf, sc[0][c], 0, 0, 0);
          sc[1][c] = __builtin_amdgcn_mfma_f32_16x16x32_bf16(qf[1][ks], kf, sc[1][c], 0, 0, 0);
        }
      }

      // ---- scale + causal mask on wave-diagonal tile ----
      float pv[2][2][4];
      const bool diag = (kt == ktmax_w);
#pragma unroll
      for (int rf = 0; rf < 2; ++rf)
#pragma unroll
        for (int c = 0; c < 2; ++c)
#pragma unroll
          for (int r = 0; r < 4; ++r) {
            float s = sc[rf][c][r] * scale2;
            if (diag && (c * 16 + lr) > (rf * 16 + lg * 4 + r)) s = -1e30f;
            pv[rf][c][r] = s;
          }

      // ---- defer-max check (no cross-lane traffic on the common path) ----
      int ok = 1;
      float lmax[2][4];
#pragma unroll
      for (int rf = 0; rf < 2; ++rf)
#pragma unroll
        for (int r = 0; r < 4; ++r) {
          lmax[rf][r] = fmaxf(pv[rf][0][r], pv[rf][1][r]);
          ok &= (lmax[rf][r] <= m[rf][r] + 8.0f);
        }
      if (!__all(ok)) {
        // slow path (rare): true row max, rescale all 13 acc columns
#pragma unroll
        for (int rf = 0; rf < 2; ++rf) {
          float rmax[4], alpha[4];
#pragma unroll
          for (int r = 0; r < 4; ++r) rmax[r] = lmax[rf][r];
#pragma unroll
          for (int off = 1; off < 16; off <<= 1) {
#pragma unroll
            for (int r = 0; r < 4; ++r) rmax[r] = fmaxf(rmax[r], __shfl_xor(rmax[r], off));
          }
#pragma unroll
          for (int r = 0; r < 4; ++r) {
            float mn = fmaxf(m[rf][r], rmax[r]);
            alpha[r] = EXP2(m[rf][r] - mn);
            m[rf][r] = mn;
          }
#pragma unroll
          for (int c = 0; c < 13; ++c)
#pragma unroll
            for (int r = 0; r < 4; ++r) acc[rf][c][r] *= alpha[r];
        }
      }

      // ---- P = exp2(pv - m) -> per-wave LDS (bf16) ----
#pragma unroll
      for (int rf = 0; rf < 2; ++rf)
#pragma unroll
        for (int c = 0; c < 2; ++c)
#pragma unroll
          for (int r = 0; r < 4; ++r)
            sP[w][rf * 16 + lg * 4 + r][c * 16 + lr] = (bf16_t)EXP2(pv[rf][c][r] - m[rf][r]);

      // ---- PV: acc[rf] += P[rf](16x32) * V(32x192) + denominator column ----
      bf16x8 pf[2];
#pragma unroll
      for (int rf = 0; rf < 2; ++rf)
        pf[rf] = *reinterpret_cast<const bf16x8*>(&sP[w][rf * 16 + lr][lg * 8]);
#pragma unroll
      for (int c2 = 0; c2 < 12; ++c2) {
        const int row = c2 * 16 + lr;
        bf16x8 vf = *reinterpret_cast<const bf16x8*>(
            &sV[cur][0] + row * KB32 + ((lg ^ (row & 3)) << 3));
        acc[0][c2] = __builtin_amdgcn_mfma_f32_16x16x32_bf16(pf[0], vf, acc[0][c2], 0, 0, 0);
        acc[1][c2] = __builtin_amdgcn_mfma_f32_16x16x32_bf16(pf[1], vf, acc[1][c2], 0, 0, 0);
      }
      acc[0][12] = __builtin_amdgcn_mfma_f32_16x16x32_bf16(pf[0], vones, acc[0][12], 0, 0, 0);
      acc[1][12] = __builtin_amdgcn_mfma_f32_16x16x32_bf16(pf[1], vones, acc[1][12], 0, 0, 0);
    }
    cur ^= 1;
  }

  // ---- epilogue: broadcast denominator (lane lr==0 of each group) ----
#pragma unroll
  for (int rf = 0; rf < 2; ++rf) {
    float rl[4];
#pragma unroll
    for (int r = 0; r < 4; ++r) rl[r] = 1.0f / __shfl(acc[rf][12][r], l & 48);
#pragma unroll
    for (int c2 = 0; c2 < 12; ++c2) {
#pragma unroll
      for (int r = 0; r < 4; ++r) {
        int i = wrow0 + rf * 16 + lg * 4 + r;
        size_t off = (size_t)(b * S_ + i) * QKD + h * DH_ + c2 * 16 + lr;
        attn[off] = (bf16_t)(acc[rf][c2][r] * rl[r]);
      }
    }
  }
}

// ---------------- launch ----------------
extern "C" void kernel_launch(void* const* d_in, const int* in_sizes, int n_in,
                              void* d_out, int out_size, void* d_ws, size_t ws_size,
                              hipStream_t stream) {
  const float* x        = (const float*)d_in[0];
  const float* w_qa     = (const float*)d_in[1];
  const float* q_norm_w = (const float*)d_in[2];
  const float* w_qb     = (const float*)d_in[3];
  const float* w_k      = (const float*)d_in[4];
  const float* w_v      = (const float*)d_in[5];
  const float* w_o      = (const float*)d_in[6];
  const float* attn_sink= (const float*)d_in[7];
  float* out = (float*)d_out;

  char* ws = (char*)d_ws;
  size_t off = 0;
  auto alloc = [&](size_t bytes) -> void* {
    void* p = ws + off;
    off += (bytes + 255) & ~(size_t)255;
    return p;
  };
  bf16_t* q_b  = (bf16_t*)alloc((size_t)NROWS * QKD * 2);
  bf16_t* k_b  = (bf16_t*)alloc((size_t)NROWS * DH_ * 2);
  bf16_t* vt_b = (bf16_t*)alloc((size_t)DH_ * NROWS * 2);
  bf16_t* wo_t = (bf16_t*)alloc((size_t)HID_ * QKD * 2);   // w_o^T [2048][3072]
  size_t temp_start = off;
  bf16_t* xb    = (bf16_t*)alloc((size_t)NROWS * HID_ * 2);
  bf16_t* wqa_t = (bf16_t*)alloc((size_t)QL_ * HID_ * 2);  // [512][2048]
  bf16_t* wqb_t = (bf16_t*)alloc((size_t)QKD * QL_ * 2);   // [3072][512]
  bf16_t* wkv_t = (bf16_t*)alloc((size_t)(2 * DH_) * HID_ * 2); // [384][2048]
  bf16_t* qa_b  = (bf16_t*)alloc((size_t)NROWS * QL_ * 2);
  bf16_t* attn_b = (bf16_t*)(ws + temp_start);             // overlays dead temps

  int n4x = (int)((size_t)NROWS * HID_ / 4);
  cast_f32_to_bf16<<<dim3((n4x + 255) / 256), dim3(256), 0, stream>>>(x, xb, n4x);
  transpose_cast<<<dim3(QL_ / 32, HID_ / 32), 256, 0, stream>>>(w_qa, wqa_t, HID_, QL_);
  transpose_cast<<<dim3(QKD / 32, QL_ / 32), 256, 0, stream>>>(w_qb, wqb_t, QL_, QKD);
  transpose_cast<<<dim3(DH_ / 32, HID_ / 32), 256, 0, stream>>>(w_k, wkv_t, HID_, DH_);
  transpose_cast<<<dim3(DH_ / 32, HID_ / 32), 256, 0, stream>>>(w_v, wkv_t + (size_t)DH_ * HID_, HID_, DH_);
  transpose_cast<<<dim3(HID_ / 32, QKD / 32), 256, 0, stream>>>(w_o, wo_t, QKD, HID_);

  // q_a = rmsnorm(x @ w_qa)
  gemm128_kernel<1><<<dim3(QL_ / 128, NROWS / 128), 256, 0, stream>>>(xb, wqa_t, qa_b, NROWS, QL_, HID_);
  rmsnorm_kernel<<<dim3(NROWS), dim3(64), 0, stream>>>(qa_b, q_norm_w);
  // q = q_a @ w_qb
  gemm128_kernel<1><<<dim3(QKD / 128, NROWS / 128), 256, 0, stream>>>(qa_b, wqb_t, q_b, NROWS, QKD, QL_);
  // k + v^T in one launch (384 column-tiles of 64)
  gemm_kv_kernel<<<dim3((2 * DH_) / BN, NROWS / BM), 256, 0, stream>>>(xb, wkv_t, k_b, vt_b);
  rope_q_kernel<<<dim3((NROWS * H_ * 32) / 256), dim3(256), 0, stream>>>(q_b);
  rope_k_kernel<<<dim3((NROWS * 32) / 256), dim3(256), 0, stream>>>(k_b);
  attn_kernel<<<dim3(16 * 32), dim3(256), 0, stream>>>(q_b, k_b, vt_b, attn_sink, attn_b);
  // out = attn @ w_o
  gemm128_kernel<0><<<dim3(HID_ / 128, NROWS / 128), 256, 0, stream>>>(attn_b, wo_t, out, NROWS, HID_, QKD);
}